// Round 3
// baseline (614.756 us; speedup 1.0000x reference)
//
#include <hip/hip_runtime.h>
#include <hip/hip_bf16.h>
#include <math.h>

#define N_NODES 20000
#define N_EDGES 640000
#define F_IN 128
#define HID 64
#define HEADS 4
#define HC 256      // HEADS*HID
#define OUT_DIM 10
#define NUM_GRAPHS 128
#define NEG_SLOPE 0.2f
#define BN_EPS 1e-5f

typedef short bf16s;
using bf16x8 = __attribute__((ext_vector_type(8))) short;
using bf16x4 = __attribute__((ext_vector_type(4))) short;
using f32x4 = __attribute__((ext_vector_type(4))) float;

__device__ __forceinline__ float bs2f(short s) {
    unsigned int u = ((unsigned int)(unsigned short)s) << 16;
    return __builtin_bit_cast(float, u);
}
__device__ __forceinline__ short f2bs(float f) {
    unsigned int u = __builtin_bit_cast(unsigned int, f);
    unsigned int r = u + 0x7FFFu + ((u >> 16) & 1u);
    return (short)(r >> 16);
}

// ---------------- utility kernels ----------------

__global__ void fill_i32(int* p, int n, int val) {
    int tid = blockIdx.x * blockDim.x + threadIdx.x;
    if (tid < n) p[tid] = val;
}

__global__ void fill_f32(float* p, int n, float val) {
    int tid = blockIdx.x * blockDim.x + threadIdx.x;
    if (tid < n) p[tid] = val;
}

__global__ void copy_i32(int* dst, const int* src, int n) {
    int tid = blockIdx.x * blockDim.x + threadIdx.x;
    if (tid < n) dst[tid] = src[tid];
}

__global__ void conv_bf16(const float* __restrict__ in, bf16s* __restrict__ out, int n4) {
    int tid = blockIdx.x * blockDim.x + threadIdx.x;
    if (tid >= n4) return;
    float4 v = reinterpret_cast<const float4*>(in)[tid];
    bf16x4 o;
    o[0] = f2bs(v.x); o[1] = f2bs(v.y); o[2] = f2bs(v.z); o[3] = f2bs(v.w);
    reinterpret_cast<bf16x4*>(out)[tid] = o;
}

// transpose W [K][256] fp32 -> Wt [256][K] bf16
__global__ void transpose_w(const float* __restrict__ W, bf16s* __restrict__ Wt, int K) {
    int tid = blockIdx.x * blockDim.x + threadIdx.x;
    if (tid >= K * HC) return;
    int c = tid / K, k = tid - c * K;
    Wt[tid] = f2bs(W[(size_t)k * HC + c]);
}

// ---------------- CSR build ----------------

__global__ void count_deg(const int* __restrict__ ei_dst, int* deg, int E) {
    int tid = blockIdx.x * blockDim.x + threadIdx.x;
    if (tid < E) atomicAdd(&deg[ei_dst[tid]], 1);
}

__global__ void scan_deg(const int* __restrict__ deg, int* __restrict__ rowptr, int n) {
    __shared__ int sdata[1024];
    __shared__ int carry;
    if (threadIdx.x == 0) { carry = 0; rowptr[0] = 0; }
    __syncthreads();
    for (int base = 0; base < n; base += 1024) {
        int i = base + threadIdx.x;
        int v = (i < n) ? deg[i] : 0;
        sdata[threadIdx.x] = v;
        __syncthreads();
        for (int off = 1; off < 1024; off <<= 1) {
            int t = (threadIdx.x >= off) ? sdata[threadIdx.x - off] : 0;
            __syncthreads();
            sdata[threadIdx.x] += t;
            __syncthreads();
        }
        int inc = sdata[threadIdx.x] + carry;
        if (i < n) rowptr[i + 1] = inc;
        __syncthreads();
        if (threadIdx.x == 1023) carry = inc;
        __syncthreads();
    }
}

__global__ void fill_csr(const int* __restrict__ ei, int* cursor, int* esrc, int E, int n) {
    int tid = blockIdx.x * blockDim.x + threadIdx.x;
    if (tid < E) {
        int src = ei[tid];
        int dst = ei[E + tid];
        int pos = atomicAdd(&cursor[dst], 1);
        esrc[pos] = src;
    } else if (tid < E + n) {
        int node = tid - E;
        int pos = atomicAdd(&cursor[node], 1);
        esrc[pos] = node;
    }
}

// graph boundaries from sorted batch: gstart[0..128]
__global__ void graph_bounds(const int* __restrict__ batch, int* __restrict__ gstart) {
    __shared__ int h[NUM_GRAPHS];
    int tid = threadIdx.x;
    if (tid < NUM_GRAPHS) h[tid] = 0;
    __syncthreads();
    for (int i = tid; i < N_NODES; i += blockDim.x) atomicAdd(&h[batch[i]], 1);
    __syncthreads();
    if (tid == 0) {
        int acc = 0;
        gstart[0] = 0;
        for (int g = 0; g < NUM_GRAPHS; g++) { acc += h[g]; gstart[g + 1] = acc; }
    }
}

// ---------------- bf16 MFMA GEMM + fused attention coefficients ----------------
// H[M,256] = A[M,K] @ Wt^T; blockIdx.y == head; epilogue computes asb/adb.

__global__ __launch_bounds__(256) void gemm_bf16(
        const bf16s* __restrict__ A, const bf16s* __restrict__ Wt,
        bf16s* __restrict__ Hout,
        const float* __restrict__ a_src, const float* __restrict__ a_dst,
        float* __restrict__ asb, float* __restrict__ adb,
        int M, int K) {
    __shared__ bf16s As[128][72];
    __shared__ bf16s Bs[64][72];
    int tid = threadIdx.x;
    int wave = tid >> 6, lane = tid & 63;
    int row0 = blockIdx.x * 128;
    int head = blockIdx.y;
    int col0 = head * 64;
    int lr = lane & 15, lk = lane >> 4;

    f32x4 acc[2][4];
    #pragma unroll
    for (int i = 0; i < 2; i++)
        #pragma unroll
        for (int j = 0; j < 4; j++)
            acc[i][j] = (f32x4){0.f, 0.f, 0.f, 0.f};

    for (int k0 = 0; k0 < K; k0 += 64) {
        #pragma unroll
        for (int i = 0; i < 4; i++) {
            int idx = tid + i * 256;
            int r = idx >> 3, ch = idx & 7;
            int gr = row0 + r;
            bf16x8 v = {};
            if (gr < M) v = *reinterpret_cast<const bf16x8*>(A + (size_t)gr * K + k0 + ch * 8);
            *reinterpret_cast<bf16x8*>(&As[r][ch * 8]) = v;
        }
        #pragma unroll
        for (int i = 0; i < 2; i++) {
            int idx = tid + i * 256;
            int r = idx >> 3, ch = idx & 7;
            bf16x8 v = *reinterpret_cast<const bf16x8*>(Wt + (size_t)(col0 + r) * K + k0 + ch * 8);
            *reinterpret_cast<bf16x8*>(&Bs[r][ch * 8]) = v;
        }
        __syncthreads();
        #pragma unroll
        for (int ks = 0; ks < 2; ks++) {
            bf16x8 bfr[4];
            #pragma unroll
            for (int j = 0; j < 4; j++)
                bfr[j] = *reinterpret_cast<const bf16x8*>(&Bs[j * 16 + lr][ks * 32 + lk * 8]);
            #pragma unroll
            for (int i = 0; i < 2; i++) {
                bf16x8 afr = *reinterpret_cast<const bf16x8*>(&As[wave * 32 + i * 16 + lr][ks * 32 + lk * 8]);
                #pragma unroll
                for (int j = 0; j < 4; j++)
                    acc[i][j] = __builtin_amdgcn_mfma_f32_16x16x32_bf16(afr, bfr[j], acc[i][j], 0, 0, 0);
            }
        }
        __syncthreads();
    }

    // store H (C/D layout: col = lane&15, row = (lane>>4)*4 + q)
    #pragma unroll
    for (int i = 0; i < 2; i++) {
        #pragma unroll
        for (int q = 0; q < 4; q++) {
            int r = row0 + wave * 32 + i * 16 + lk * 4 + q;
            if (r < M) {
                #pragma unroll
                for (int j = 0; j < 4; j++) {
                    int c = col0 + j * 16 + lr;
                    Hout[(size_t)r * HC + c] = f2bs(acc[i][j][q]);
                }
            }
        }
    }

    // fused attn coefficients: per-row dot with a_src/a_dst for this head
    float asv0 = a_src[col0 + 0 * 16 + lr], asv1 = a_src[col0 + 1 * 16 + lr];
    float asv2 = a_src[col0 + 2 * 16 + lr], asv3 = a_src[col0 + 3 * 16 + lr];
    float adv0 = a_dst[col0 + 0 * 16 + lr], adv1 = a_dst[col0 + 1 * 16 + lr];
    float adv2 = a_dst[col0 + 2 * 16 + lr], adv3 = a_dst[col0 + 3 * 16 + lr];
    #pragma unroll
    for (int i = 0; i < 2; i++) {
        #pragma unroll
        for (int q = 0; q < 4; q++) {
            float ps = acc[i][0][q] * asv0 + acc[i][1][q] * asv1 + acc[i][2][q] * asv2 + acc[i][3][q] * asv3;
            float pd = acc[i][0][q] * adv0 + acc[i][1][q] * adv1 + acc[i][2][q] * adv2 + acc[i][3][q] * adv3;
            #pragma unroll
            for (int off = 1; off < 16; off <<= 1) {
                ps += __shfl_xor(ps, off);
                pd += __shfl_xor(pd, off);
            }
            int r = row0 + wave * 32 + i * 16 + lk * 4 + q;
            if (lr == 0 && r < M) {
                asb[r * HEADS + head] = ps;
                adb[r * HEADS + head] = pd;
            }
        }
    }
}

// ---------------- GAT aggregation (fused: online softmax + BN stats / head-mean) ----------------

__device__ __forceinline__ float lrelu(float x) { return x > 0.f ? x : NEG_SLOPE * x; }

// MODE 0: BN layer -> write out [N,HC] fp32 (+bias) and accumulate colsum/colsq
// MODE 1: layer 3  -> head-mean + b3 -> write xs2 [N,HID]
template<int MODE>
__global__ __launch_bounds__(256) void gat_aggregate(
        const bf16s* __restrict__ hfeat,
        const float* __restrict__ asb, const float* __restrict__ adb,
        const int* __restrict__ rowptr, const int* __restrict__ esrc,
        const float* __restrict__ bias,   // [HC] (MODE 0) or b3 [HID] (MODE 1)
        float* __restrict__ out,          // [N,HC] (MODE 0) or xs2 [N,HID] (MODE 1)
        float* __restrict__ colsum, float* __restrict__ colsq) {
    __shared__ float4 alpha_lds[4][128];
    __shared__ float bnsum[4][256];
    __shared__ float bnsq[4][256];

    int wid = threadIdx.x >> 6, lane = threadIdx.x & 63;
    int d = blockIdx.x * 4 + wid;   // grid sized so d < N_NODES always
    int start = rowptr[d], end = rowptr[d + 1];

    float adv0 = adb[d * HEADS + 0], adv1 = adb[d * HEADS + 1];
    float adv2 = adb[d * HEADS + 2], adv3 = adb[d * HEADS + 3];

    // ---- online softmax pass (max + sum fused) ----
    float m0 = -1e30f, m1 = -1e30f, m2 = -1e30f, m3 = -1e30f;
    float s0 = 0.f, s1 = 0.f, s2 = 0.f, s3 = 0.f;
    float e00 = 0.f, e01 = 0.f, e02 = 0.f, e03 = 0.f;
    float e10 = 0.f, e11 = 0.f, e12 = 0.f, e13 = 0.f;
    int k = 0;
    for (int j = start + lane; j < end; j += 64, k++) {
        int s = esrc[j];
        const float4 av = *reinterpret_cast<const float4*>(asb + (size_t)s * HEADS);
        float x0 = lrelu(av.x + adv0), x1 = lrelu(av.y + adv1);
        float x2 = lrelu(av.z + adv2), x3 = lrelu(av.w + adv3);
        if (k == 0)      { e00 = x0; e01 = x1; e02 = x2; e03 = x3; }
        else if (k == 1) { e10 = x0; e11 = x1; e12 = x2; e13 = x3; }
        float n0 = fmaxf(m0, x0); s0 = s0 * __expf(m0 - n0) + __expf(x0 - n0); m0 = n0;
        float n1 = fmaxf(m1, x1); s1 = s1 * __expf(m1 - n1) + __expf(x1 - n1); m1 = n1;
        float n2 = fmaxf(m2, x2); s2 = s2 * __expf(m2 - n2) + __expf(x2 - n2); m2 = n2;
        float n3 = fmaxf(m3, x3); s3 = s3 * __expf(m3 - n3) + __expf(x3 - n3); m3 = n3;
    }
    #pragma unroll
    for (int off = 1; off < 64; off <<= 1) {
        float om, os, nn;
        om = __shfl_xor(m0, off); os = __shfl_xor(s0, off);
        nn = fmaxf(m0, om); s0 = s0 * __expf(m0 - nn) + os * __expf(om - nn); m0 = nn;
        om = __shfl_xor(m1, off); os = __shfl_xor(s1, off);
        nn = fmaxf(m1, om); s1 = s1 * __expf(m1 - nn) + os * __expf(om - nn); m1 = nn;
        om = __shfl_xor(m2, off); os = __shfl_xor(s2, off);
        nn = fmaxf(m2, om); s2 = s2 * __expf(m2 - nn) + os * __expf(om - nn); m2 = nn;
        om = __shfl_xor(m3, off); os = __shfl_xor(s3, off);
        nn = fmaxf(m3, om); s3 = s3 * __expf(m3 - nn) + os * __expf(om - nn); m3 = nn;
    }
    float rr0 = 1.f / (s0 + 1e-16f), rr1 = 1.f / (s1 + 1e-16f);
    float rr2 = 1.f / (s2 + 1e-16f), rr3 = 1.f / (s3 + 1e-16f);

    // ---- stash per-edge alphas for first 128 edges (idx = lane + 64k < 128) ----
    {
        int j = start + lane;
        if (j < end) {
            float4 a;
            a.x = __expf(e00 - m0) * rr0; a.y = __expf(e01 - m1) * rr1;
            a.z = __expf(e02 - m2) * rr2; a.w = __expf(e03 - m3) * rr3;
            alpha_lds[wid][lane] = a;
        }
        j = start + 64 + lane;
        if (j < end) {
            float4 a;
            a.x = __expf(e10 - m0) * rr0; a.y = __expf(e11 - m1) * rr1;
            a.z = __expf(e12 - m2) * rr2; a.w = __expf(e13 - m3) * rr3;
            alpha_lds[wid][64 + lane] = a;
        }
    }

    // ---- weighted accumulate: 2 edges/iter, lane owns 8 cols ----
    int half = lane >> 5;
    int cl = lane & 31;
    int hsel = cl >> 3;
    float mh  = (hsel == 0) ? m0 : (hsel == 1) ? m1 : (hsel == 2) ? m2 : m3;
    float rdh = (hsel == 0) ? rr0 : (hsel == 1) ? rr1 : (hsel == 2) ? rr2 : rr3;
    float adh = (hsel == 0) ? adv0 : (hsel == 1) ? adv1 : (hsel == 2) ? adv2 : adv3;

    float av0 = 0.f, av1 = 0.f, av2 = 0.f, av3 = 0.f;
    float av4 = 0.f, av5 = 0.f, av6 = 0.f, av7 = 0.f;
    for (int j = start; j < end; j += 2) {
        int jj = j + half;
        if (jj < end) {
            int idx = jj - start;
            int s = esrc[jj];
            float alpha;
            if (idx < 128) {
                alpha = reinterpret_cast<const float*>(&alpha_lds[wid][idx])[hsel];
            } else {
                float e = lrelu(asb[(size_t)s * HEADS + hsel] + adh);
                alpha = __expf(e - mh) * rdh;
            }
            const bf16x8 v = *reinterpret_cast<const bf16x8*>(hfeat + (size_t)s * HC + cl * 8);
            av0 += alpha * bs2f(v[0]); av1 += alpha * bs2f(v[1]);
            av2 += alpha * bs2f(v[2]); av3 += alpha * bs2f(v[3]);
            av4 += alpha * bs2f(v[4]); av5 += alpha * bs2f(v[5]);
            av6 += alpha * bs2f(v[6]); av7 += alpha * bs2f(v[7]);
        }
    }
    av0 += __shfl_xor(av0, 32); av1 += __shfl_xor(av1, 32);
    av2 += __shfl_xor(av2, 32); av3 += __shfl_xor(av3, 32);
    av4 += __shfl_xor(av4, 32); av5 += __shfl_xor(av5, 32);
    av6 += __shfl_xor(av6, 32); av7 += __shfl_xor(av7, 32);

    if constexpr (MODE == 0) {
        // add bias, write row, stash BN partials
        if (half == 0) {
            const float4 b0 = *reinterpret_cast<const float4*>(bias + cl * 8);
            const float4 b1 = *reinterpret_cast<const float4*>(bias + cl * 8 + 4);
            av0 += b0.x; av1 += b0.y; av2 += b0.z; av3 += b0.w;
            av4 += b1.x; av5 += b1.y; av6 += b1.z; av7 += b1.w;
            float4 o0; o0.x = av0; o0.y = av1; o0.z = av2; o0.w = av3;
            float4 o1; o1.x = av4; o1.y = av5; o1.z = av6; o1.w = av7;
            *reinterpret_cast<float4*>(out + (size_t)d * HC + cl * 8) = o0;
            *reinterpret_cast<float4*>(out + (size_t)d * HC + cl * 8 + 4) = o1;
            int c = cl * 8;
            bnsum[wid][c + 0] = av0; bnsq[wid][c + 0] = av0 * av0;
            bnsum[wid][c + 1] = av1; bnsq[wid][c + 1] = av1 * av1;
            bnsum[wid][c + 2] = av2; bnsq[wid][c + 2] = av2 * av2;
            bnsum[wid][c + 3] = av3; bnsq[wid][c + 3] = av3 * av3;
            bnsum[wid][c + 4] = av4; bnsq[wid][c + 4] = av4 * av4;
            bnsum[wid][c + 5] = av5; bnsq[wid][c + 5] = av5 * av5;
            bnsum[wid][c + 6] = av6; bnsq[wid][c + 6] = av6 * av6;
            bnsum[wid][c + 7] = av7; bnsq[wid][c + 7] = av7 * av7;
        }
        __syncthreads();
        int t = threadIdx.x;  // 256 threads == 256 cols
        float ss = bnsum[0][t] + bnsum[1][t] + bnsum[2][t] + bnsum[3][t];
        float qq = bnsq[0][t] + bnsq[1][t] + bnsq[2][t] + bnsq[3][t];
        atomicAdd(&colsum[t], ss);
        atomicAdd(&colsq[t], qq);
    } else {
        // head mean: reduce over lane bits 3,4 (the 4 heads)
        float h0 = av0 + __shfl_xor(av0, 8); h0 += __shfl_xor(h0, 16);
        float h1 = av1 + __shfl_xor(av1, 8); h1 += __shfl_xor(h1, 16);
        float h2 = av2 + __shfl_xor(av2, 8); h2 += __shfl_xor(h2, 16);
        float h3 = av3 + __shfl_xor(av3, 8); h3 += __shfl_xor(h3, 16);
        float h4 = av4 + __shfl_xor(av4, 8); h4 += __shfl_xor(h4, 16);
        float h5 = av5 + __shfl_xor(av5, 8); h5 += __shfl_xor(h5, 16);
        float h6 = av6 + __shfl_xor(av6, 8); h6 += __shfl_xor(h6, 16);
        float h7 = av7 + __shfl_xor(av7, 8); h7 += __shfl_xor(h7, 16);
        if (half == 0 && cl < 8) {
            int c = cl * 8;
            float4 o0, o1;
            o0.x = 0.25f * h0 + bias[c + 0]; o0.y = 0.25f * h1 + bias[c + 1];
            o0.z = 0.25f * h2 + bias[c + 2]; o0.w = 0.25f * h3 + bias[c + 3];
            o1.x = 0.25f * h4 + bias[c + 4]; o1.y = 0.25f * h5 + bias[c + 5];
            o1.z = 0.25f * h6 + bias[c + 6]; o1.w = 0.25f * h7 + bias[c + 7];
            *reinterpret_cast<float4*>(out + (size_t)d * HID + c) = o0;
            *reinterpret_cast<float4*>(out + (size_t)d * HID + c + 4) = o1;
        }
    }
}

// ---------------- BatchNorm finalize + apply ----------------

__global__ void bn_finalize(const float* colsum, const float* colsq,
                            const float* __restrict__ g, const float* __restrict__ be,
                            float* scale, float* shift, int n) {
    int col = threadIdx.x;  // 256
    float mu = colsum[col] / (float)n;
    float var = colsq[col] / (float)n - mu * mu;
    float sc = g[col] * rsqrtf(var + BN_EPS);
    scale[col] = sc;
    shift[col] = be[col] - mu * sc;
}

__global__ void bn_apply_elu(const float* __restrict__ x,
                             const float* __restrict__ scale, const float* __restrict__ shift,
                             float* __restrict__ xs_out, bf16s* __restrict__ act, int n) {
    int col = threadIdx.x;  // 256
    float sc = scale[col], sh = shift[col];
    for (int r = blockIdx.x; r < n; r += gridDim.x) {
        float v = x[(size_t)r * HC + col];
        float y = v * sc + sh;
        xs_out[(size_t)r * HC + col] = y;
        float e = y > 0.f ? y : __expf(y) - 1.f;
        act[(size_t)r * HC + col] = f2bs(e);
    }
}

// ---------------- pool (no atomics) + final linear ----------------

__global__ void pool_graphs(const float* __restrict__ xs2, const int* __restrict__ gstart,
                            float* __restrict__ pooled) {
    int g = blockIdx.x * (blockDim.x >> 6) + (threadIdx.x >> 6);
    int lane = threadIdx.x & 63;
    if (g >= NUM_GRAPHS) return;
    int a = gstart[g], b = gstart[g + 1];
    float acc = 0.f;
    for (int n = a; n < b; n++) acc += xs2[(size_t)n * HID + lane];
    pooled[g * HID + lane] = acc / fmaxf((float)(b - a), 1.f);
}

__global__ void final_linear(const float* __restrict__ pooled, const float* __restrict__ Wlin,
                             const float* __restrict__ blin, float* __restrict__ out) {
    int tid = blockIdx.x * blockDim.x + threadIdx.x;
    if (tid >= NUM_GRAPHS * OUT_DIM) return;
    int g = tid / OUT_DIM, o = tid % OUT_DIM;
    float s = blin[o];
    for (int c = 0; c < HID; ++c) s += pooled[g * HID + c] * Wlin[c * OUT_DIM + o];
    out[g * OUT_DIM + o] = s;
}

// ---------------- host side ----------------

extern "C" void kernel_launch(void* const* d_in, const int* in_sizes, int n_in,
                              void* d_out, int out_size, void* d_ws, size_t ws_size,
                              hipStream_t stream) {
    const float* x     = (const float*)d_in[0];
    const int*   ei    = (const int*)d_in[1];   // [2,E]
    const int*   batch = (const int*)d_in[2];
    const float* W1  = (const float*)d_in[3];
    const float* as1 = (const float*)d_in[4];
    const float* ad1 = (const float*)d_in[5];
    const float* b1  = (const float*)d_in[6];
    const float* g1  = (const float*)d_in[7];
    const float* be1 = (const float*)d_in[8];
    const float* W2  = (const float*)d_in[9];
    const float* as2 = (const float*)d_in[10];
    const float* ad2 = (const float*)d_in[11];
    const float* b2  = (const float*)d_in[12];
    const float* g2  = (const float*)d_in[13];
    const float* be2 = (const float*)d_in[14];
    const float* W3  = (const float*)d_in[15];
    const float* as3 = (const float*)d_in[16];
    const float* ad3 = (const float*)d_in[17];
    const float* b3  = (const float*)d_in[18];
    const float* Wlin = (const float*)d_in[19];
    const float* blin = (const float*)d_in[20];

    // output regions
    float* out_final = (float*)d_out;                 // [128,10]
    float* xs0 = out_final + NUM_GRAPHS * OUT_DIM;    // [N,256]
    float* xs1 = xs0 + (size_t)N_NODES * HC;          // [N,256]
    float* xs2 = xs1 + (size_t)N_NODES * HC;          // [N,64]
    float* pooled_out = xs2 + (size_t)N_NODES * HID;  // [128,64]

    // workspace carve
    char* p = (char*)d_ws;
    auto alloc = [&](size_t bytes) { char* r = p; p += (bytes + 255) & ~(size_t)255; return (void*)r; };
    bf16s* hfeat  = (bf16s*)alloc((size_t)N_NODES * HC * 2);
    bf16s* actC   = (bf16s*)alloc((size_t)N_NODES * HC * 2);
    bf16s* xb     = (bf16s*)alloc((size_t)N_NODES * F_IN * 2);
    float* gatB   = (float*)alloc((size_t)N_NODES * HC * 4);
    bf16s* Wt1    = (bf16s*)alloc((size_t)HC * F_IN * 2);
    bf16s* Wt2    = (bf16s*)alloc((size_t)HC * HC * 2);
    bf16s* Wt3    = (bf16s*)alloc((size_t)HC * HC * 2);
    float* asb    = (float*)alloc((size_t)N_NODES * HEADS * 4);
    float* adb    = (float*)alloc((size_t)N_NODES * HEADS * 4);
    int*   deg    = (int*)alloc((size_t)N_NODES * 4);
    int*   rowptr = (int*)alloc((size_t)(N_NODES + 1) * 4);
    int*   esrc   = (int*)alloc((size_t)(N_EDGES + N_NODES) * 4);
    float* colstats = (float*)alloc(2 * HC * 4);
    float* colsum = colstats;
    float* colsq  = colstats + HC;
    float* scale  = (float*)alloc(HC * 4);
    float* shift  = (float*)alloc(HC * 4);
    int*   gstart = (int*)alloc((NUM_GRAPHS + 1) * 4);

    const int ETOT = N_EDGES + N_NODES;

    // ---- CSR build (once, reused for all 3 layers) ----
    fill_i32<<<(N_NODES + 255) / 256, 256, 0, stream>>>(deg, N_NODES, 1);  // self-loop
    count_deg<<<(N_EDGES + 255) / 256, 256, 0, stream>>>(ei + N_EDGES, deg, N_EDGES);
    scan_deg<<<1, 1024, 0, stream>>>(deg, rowptr, N_NODES);
    copy_i32<<<(N_NODES + 255) / 256, 256, 0, stream>>>(deg, rowptr, N_NODES);
    fill_csr<<<(ETOT + 255) / 256, 256, 0, stream>>>(ei, deg, esrc, N_EDGES, N_NODES);
    graph_bounds<<<1, 1024, 0, stream>>>(batch, gstart);

    // ---- weight prep ----
    conv_bf16<<<((N_NODES * F_IN / 4) + 255) / 256, 256, 0, stream>>>(x, xb, N_NODES * F_IN / 4);
    transpose_w<<<(HC * F_IN + 255) / 256, 256, 0, stream>>>(W1, Wt1, F_IN);
    transpose_w<<<(HC * HC + 255) / 256, 256, 0, stream>>>(W2, Wt2, HC);
    transpose_w<<<(HC * HC + 255) / 256, 256, 0, stream>>>(W3, Wt3, HC);

    int agg_blocks = N_NODES / 4;   // exactly 4 waves/block, no remainder
    dim3 ggrid((N_NODES + 127) / 128, HEADS);

    // ---- layer 1 ----
    {
        gemm_bf16<<<ggrid, 256, 0, stream>>>(xb, Wt1, hfeat, as1, ad1, asb, adb, N_NODES, F_IN);
        fill_f32<<<2, 256, 0, stream>>>(colstats, 2 * HC, 0.f);
        gat_aggregate<0><<<agg_blocks, 256, 0, stream>>>(hfeat, asb, adb, rowptr, esrc, b1, gatB, colsum, colsq);
        bn_finalize<<<1, 256, 0, stream>>>(colsum, colsq, g1, be1, scale, shift, N_NODES);
        bn_apply_elu<<<2048, 256, 0, stream>>>(gatB, scale, shift, xs0, actC, N_NODES);
    }
    // ---- layer 2 ----
    {
        gemm_bf16<<<ggrid, 256, 0, stream>>>(actC, Wt2, hfeat, as2, ad2, asb, adb, N_NODES, HC);
        fill_f32<<<2, 256, 0, stream>>>(colstats, 2 * HC, 0.f);
        gat_aggregate<0><<<agg_blocks, 256, 0, stream>>>(hfeat, asb, adb, rowptr, esrc, b2, gatB, colsum, colsq);
        bn_finalize<<<1, 256, 0, stream>>>(colsum, colsq, g2, be2, scale, shift, N_NODES);
        bn_apply_elu<<<2048, 256, 0, stream>>>(gatB, scale, shift, xs1, actC, N_NODES);
    }
    // ---- layer 3 ----
    {
        gemm_bf16<<<ggrid, 256, 0, stream>>>(actC, Wt3, hfeat, as3, ad3, asb, adb, N_NODES, HC);
        gat_aggregate<1><<<agg_blocks, 256, 0, stream>>>(hfeat, asb, adb, rowptr, esrc, b3, xs2, nullptr, nullptr);
    }
    // ---- pool + final linear ----
    pool_graphs<<<NUM_GRAPHS / 4, 256, 0, stream>>>(xs2, gstart, pooled_out);
    final_linear<<<(NUM_GRAPHS * OUT_DIM + 255) / 256, 256, 0, stream>>>(pooled_out, Wlin, blin, out_final);
}

// Round 4
// 485.157 us; speedup vs baseline: 1.2671x; 1.2671x over previous
//
#include <hip/hip_runtime.h>
#include <hip/hip_bf16.h>
#include <math.h>

#define N_NODES 20000
#define N_EDGES 640000
#define F_IN 128
#define HID 64
#define HEADS 4
#define HC 256      // HEADS*HID
#define OUT_DIM 10
#define NUM_GRAPHS 128
#define NEG_SLOPE 0.2f
#define BN_EPS 1e-5f

typedef short bf16s;
using bf16x8 = __attribute__((ext_vector_type(8))) short;
using bf16x4 = __attribute__((ext_vector_type(4))) short;
using f32x4 = __attribute__((ext_vector_type(4))) float;

__device__ __forceinline__ float bs2f(short s) {
    unsigned int u = ((unsigned int)(unsigned short)s) << 16;
    return __builtin_bit_cast(float, u);
}
__device__ __forceinline__ short f2bs(float f) {
    unsigned int u = __builtin_bit_cast(unsigned int, f);
    unsigned int r = u + 0x7FFFu + ((u >> 16) & 1u);
    return (short)(r >> 16);
}

// ---------------- utility kernels ----------------

__global__ void fill_i32(int* p, int n, int val) {
    int tid = blockIdx.x * blockDim.x + threadIdx.x;
    if (tid < n) p[tid] = val;
}

__global__ void fill_f32(float* p, int n, float val) {
    int tid = blockIdx.x * blockDim.x + threadIdx.x;
    if (tid < n) p[tid] = val;
}

__global__ void copy_i32(int* dst, const int* src, int n) {
    int tid = blockIdx.x * blockDim.x + threadIdx.x;
    if (tid < n) dst[tid] = src[tid];
}

__global__ void conv_bf16(const float* __restrict__ in, bf16s* __restrict__ out, int n4) {
    int tid = blockIdx.x * blockDim.x + threadIdx.x;
    if (tid >= n4) return;
    float4 v = reinterpret_cast<const float4*>(in)[tid];
    bf16x4 o;
    o[0] = f2bs(v.x); o[1] = f2bs(v.y); o[2] = f2bs(v.z); o[3] = f2bs(v.w);
    reinterpret_cast<bf16x4*>(out)[tid] = o;
}

// transpose W [K][256] fp32 -> Wt [256][K] bf16
__global__ void transpose_w(const float* __restrict__ W, bf16s* __restrict__ Wt, int K) {
    int tid = blockIdx.x * blockDim.x + threadIdx.x;
    if (tid >= K * HC) return;
    int c = tid / K, k = tid - c * K;
    Wt[tid] = f2bs(W[(size_t)k * HC + c]);
}

// ---------------- CSR build ----------------

__global__ void count_deg(const int* __restrict__ ei_dst, int* deg, int E) {
    int tid = blockIdx.x * blockDim.x + threadIdx.x;
    if (tid < E) atomicAdd(&deg[ei_dst[tid]], 1);
}

__global__ void scan_deg(const int* __restrict__ deg, int* __restrict__ rowptr, int n) {
    __shared__ int sdata[1024];
    __shared__ int carry;
    if (threadIdx.x == 0) { carry = 0; rowptr[0] = 0; }
    __syncthreads();
    for (int base = 0; base < n; base += 1024) {
        int i = base + threadIdx.x;
        int v = (i < n) ? deg[i] : 0;
        sdata[threadIdx.x] = v;
        __syncthreads();
        for (int off = 1; off < 1024; off <<= 1) {
            int t = (threadIdx.x >= off) ? sdata[threadIdx.x - off] : 0;
            __syncthreads();
            sdata[threadIdx.x] += t;
            __syncthreads();
        }
        int inc = sdata[threadIdx.x] + carry;
        if (i < n) rowptr[i + 1] = inc;
        __syncthreads();
        if (threadIdx.x == 1023) carry = inc;
        __syncthreads();
    }
}

__global__ void fill_csr(const int* __restrict__ ei, int* cursor, int* esrc, int E, int n) {
    int tid = blockIdx.x * blockDim.x + threadIdx.x;
    if (tid < E) {
        int src = ei[tid];
        int dst = ei[E + tid];
        int pos = atomicAdd(&cursor[dst], 1);
        esrc[pos] = src;
    } else if (tid < E + n) {
        int node = tid - E;
        int pos = atomicAdd(&cursor[node], 1);
        esrc[pos] = node;
    }
}

// graph boundaries from sorted batch: gstart[0..128]
__global__ void graph_bounds(const int* __restrict__ batch, int* __restrict__ gstart) {
    __shared__ int h[NUM_GRAPHS];
    int tid = threadIdx.x;
    if (tid < NUM_GRAPHS) h[tid] = 0;
    __syncthreads();
    for (int i = tid; i < N_NODES; i += blockDim.x) atomicAdd(&h[batch[i]], 1);
    __syncthreads();
    if (tid == 0) {
        int acc = 0;
        gstart[0] = 0;
        for (int g = 0; g < NUM_GRAPHS; g++) { acc += h[g]; gstart[g + 1] = acc; }
    }
}

// ---------------- bf16 MFMA GEMM + fused attention coefficients ----------------
// H[M,256] = A[M,K] @ Wt^T; blockIdx.y == head; epilogue computes asb/adb.

__global__ __launch_bounds__(256) void gemm_bf16(
        const bf16s* __restrict__ A, const bf16s* __restrict__ Wt,
        bf16s* __restrict__ Hout,
        const float* __restrict__ a_src, const float* __restrict__ a_dst,
        float* __restrict__ asb, float* __restrict__ adb,
        int M, int K) {
    __shared__ bf16s As[128][72];
    __shared__ bf16s Bs[64][72];
    int tid = threadIdx.x;
    int wave = tid >> 6, lane = tid & 63;
    int row0 = blockIdx.x * 128;
    int head = blockIdx.y;
    int col0 = head * 64;
    int lr = lane & 15, lk = lane >> 4;

    f32x4 acc[2][4];
    #pragma unroll
    for (int i = 0; i < 2; i++)
        #pragma unroll
        for (int j = 0; j < 4; j++)
            acc[i][j] = (f32x4){0.f, 0.f, 0.f, 0.f};

    for (int k0 = 0; k0 < K; k0 += 64) {
        #pragma unroll
        for (int i = 0; i < 4; i++) {
            int idx = tid + i * 256;
            int r = idx >> 3, ch = idx & 7;
            int gr = row0 + r;
            bf16x8 v = {};
            if (gr < M) v = *reinterpret_cast<const bf16x8*>(A + (size_t)gr * K + k0 + ch * 8);
            *reinterpret_cast<bf16x8*>(&As[r][ch * 8]) = v;
        }
        #pragma unroll
        for (int i = 0; i < 2; i++) {
            int idx = tid + i * 256;
            int r = idx >> 3, ch = idx & 7;
            bf16x8 v = *reinterpret_cast<const bf16x8*>(Wt + (size_t)(col0 + r) * K + k0 + ch * 8);
            *reinterpret_cast<bf16x8*>(&Bs[r][ch * 8]) = v;
        }
        __syncthreads();
        #pragma unroll
        for (int ks = 0; ks < 2; ks++) {
            bf16x8 bfr[4];
            #pragma unroll
            for (int j = 0; j < 4; j++)
                bfr[j] = *reinterpret_cast<const bf16x8*>(&Bs[j * 16 + lr][ks * 32 + lk * 8]);
            #pragma unroll
            for (int i = 0; i < 2; i++) {
                bf16x8 afr = *reinterpret_cast<const bf16x8*>(&As[wave * 32 + i * 16 + lr][ks * 32 + lk * 8]);
                #pragma unroll
                for (int j = 0; j < 4; j++)
                    acc[i][j] = __builtin_amdgcn_mfma_f32_16x16x32_bf16(afr, bfr[j], acc[i][j], 0, 0, 0);
            }
        }
        __syncthreads();
    }

    // store H (C/D layout: col = lane&15, row = (lane>>4)*4 + q)
    #pragma unroll
    for (int i = 0; i < 2; i++) {
        #pragma unroll
        for (int q = 0; q < 4; q++) {
            int r = row0 + wave * 32 + i * 16 + lk * 4 + q;
            if (r < M) {
                #pragma unroll
                for (int j = 0; j < 4; j++) {
                    int c = col0 + j * 16 + lr;
                    Hout[(size_t)r * HC + c] = f2bs(acc[i][j][q]);
                }
            }
        }
    }

    // fused attn coefficients: per-row dot with a_src/a_dst for this head
    float asv0 = a_src[col0 + 0 * 16 + lr], asv1 = a_src[col0 + 1 * 16 + lr];
    float asv2 = a_src[col0 + 2 * 16 + lr], asv3 = a_src[col0 + 3 * 16 + lr];
    float adv0 = a_dst[col0 + 0 * 16 + lr], adv1 = a_dst[col0 + 1 * 16 + lr];
    float adv2 = a_dst[col0 + 2 * 16 + lr], adv3 = a_dst[col0 + 3 * 16 + lr];
    #pragma unroll
    for (int i = 0; i < 2; i++) {
        #pragma unroll
        for (int q = 0; q < 4; q++) {
            float ps = acc[i][0][q] * asv0 + acc[i][1][q] * asv1 + acc[i][2][q] * asv2 + acc[i][3][q] * asv3;
            float pd = acc[i][0][q] * adv0 + acc[i][1][q] * adv1 + acc[i][2][q] * adv2 + acc[i][3][q] * adv3;
            #pragma unroll
            for (int off = 1; off < 16; off <<= 1) {
                ps += __shfl_xor(ps, off);
                pd += __shfl_xor(pd, off);
            }
            int r = row0 + wave * 32 + i * 16 + lk * 4 + q;
            if (lr == 0 && r < M) {
                asb[r * HEADS + head] = ps;
                adb[r * HEADS + head] = pd;
            }
        }
    }
}

// ---------------- GAT aggregation: wave per destination, two-pass softmax ----------------

__device__ __forceinline__ float lrelu(float x) { return x > 0.f ? x : NEG_SLOPE * x; }

// MODE 0: write out [N,HC] fp32 (+bias)
// MODE 1: head-mean + b3 -> write xs2 [N,HID]
template<int MODE>
__global__ __launch_bounds__(256) void gat_aggregate(
        const bf16s* __restrict__ hfeat,
        const float* __restrict__ asb, const float* __restrict__ adb,
        const int* __restrict__ rowptr, const int* __restrict__ esrc,
        const float* __restrict__ bias,   // [HC] (MODE 0) or b3 [HID] (MODE 1)
        float* __restrict__ out) {        // [N,HC] (MODE 0) or xs2 [N,HID] (MODE 1)
    int d = blockIdx.x * 4 + (threadIdx.x >> 6);   // grid exact: 4 waves/block
    int lane = threadIdx.x & 63;
    int start = rowptr[d], end = rowptr[d + 1];

    float adv0 = adb[d * HEADS + 0], adv1 = adb[d * HEADS + 1];
    float adv2 = adb[d * HEADS + 2], adv3 = adb[d * HEADS + 3];

    // pass 1: per-head max (no exp)
    float m0 = -1e30f, m1 = -1e30f, m2 = -1e30f, m3 = -1e30f;
    for (int j = start + lane; j < end; j += 64) {
        int s = esrc[j];
        const float4 av = *reinterpret_cast<const float4*>(asb + (size_t)s * HEADS);
        m0 = fmaxf(m0, lrelu(av.x + adv0));
        m1 = fmaxf(m1, lrelu(av.y + adv1));
        m2 = fmaxf(m2, lrelu(av.z + adv2));
        m3 = fmaxf(m3, lrelu(av.w + adv3));
    }
    #pragma unroll
    for (int off = 32; off > 0; off >>= 1) {
        m0 = fmaxf(m0, __shfl_xor(m0, off));
        m1 = fmaxf(m1, __shfl_xor(m1, off));
        m2 = fmaxf(m2, __shfl_xor(m2, off));
        m3 = fmaxf(m3, __shfl_xor(m3, off));
    }

    // pass 2: per-head sum of exp(e - m)
    float s0 = 0.f, s1 = 0.f, s2 = 0.f, s3 = 0.f;
    for (int j = start + lane; j < end; j += 64) {
        int s = esrc[j];
        const float4 av = *reinterpret_cast<const float4*>(asb + (size_t)s * HEADS);
        s0 += __expf(lrelu(av.x + adv0) - m0);
        s1 += __expf(lrelu(av.y + adv1) - m1);
        s2 += __expf(lrelu(av.z + adv2) - m2);
        s3 += __expf(lrelu(av.w + adv3) - m3);
    }
    #pragma unroll
    for (int off = 32; off > 0; off >>= 1) {
        s0 += __shfl_xor(s0, off);
        s1 += __shfl_xor(s1, off);
        s2 += __shfl_xor(s2, off);
        s3 += __shfl_xor(s3, off);
    }
    float r0 = 1.f / (s0 + 1e-16f), r1 = 1.f / (s1 + 1e-16f);
    float r2 = 1.f / (s2 + 1e-16f), r3 = 1.f / (s3 + 1e-16f);

    // pass 3: 2 edges/iter; lanes 0-31 edge j, lanes 32-63 edge j+1; lane owns 8 cols
    int half = lane >> 5;
    int cl = lane & 31;
    int hsel = cl >> 3;
    float mh  = (hsel == 0) ? m0 : (hsel == 1) ? m1 : (hsel == 2) ? m2 : m3;
    float rdh = (hsel == 0) ? r0 : (hsel == 1) ? r1 : (hsel == 2) ? r2 : r3;
    float adh = (hsel == 0) ? adv0 : (hsel == 1) ? adv1 : (hsel == 2) ? adv2 : adv3;

    float av0 = 0.f, av1 = 0.f, av2 = 0.f, av3 = 0.f;
    float av4 = 0.f, av5 = 0.f, av6 = 0.f, av7 = 0.f;
    for (int j = start; j < end; j += 2) {
        int jj = j + half;
        if (jj < end) {
            int s = esrc[jj];
            float e = lrelu(asb[(size_t)s * HEADS + hsel] + adh);
            float alpha = __expf(e - mh) * rdh;
            const bf16x8 v = *reinterpret_cast<const bf16x8*>(hfeat + (size_t)s * HC + cl * 8);
            av0 += alpha * bs2f(v[0]); av1 += alpha * bs2f(v[1]);
            av2 += alpha * bs2f(v[2]); av3 += alpha * bs2f(v[3]);
            av4 += alpha * bs2f(v[4]); av5 += alpha * bs2f(v[5]);
            av6 += alpha * bs2f(v[6]); av7 += alpha * bs2f(v[7]);
        }
    }
    av0 += __shfl_xor(av0, 32); av1 += __shfl_xor(av1, 32);
    av2 += __shfl_xor(av2, 32); av3 += __shfl_xor(av3, 32);
    av4 += __shfl_xor(av4, 32); av5 += __shfl_xor(av5, 32);
    av6 += __shfl_xor(av6, 32); av7 += __shfl_xor(av7, 32);

    if constexpr (MODE == 0) {
        if (half == 0) {
            const float4 b0 = *reinterpret_cast<const float4*>(bias + cl * 8);
            const float4 b1 = *reinterpret_cast<const float4*>(bias + cl * 8 + 4);
            av0 += b0.x; av1 += b0.y; av2 += b0.z; av3 += b0.w;
            av4 += b1.x; av5 += b1.y; av6 += b1.z; av7 += b1.w;
            float4 o0; o0.x = av0; o0.y = av1; o0.z = av2; o0.w = av3;
            float4 o1; o1.x = av4; o1.y = av5; o1.z = av6; o1.w = av7;
            *reinterpret_cast<float4*>(out + (size_t)d * HC + cl * 8) = o0;
            *reinterpret_cast<float4*>(out + (size_t)d * HC + cl * 8 + 4) = o1;
        }
    } else {
        // head mean: reduce over lane bits 3,4 (the 4 heads)
        float h0 = av0 + __shfl_xor(av0, 8); h0 += __shfl_xor(h0, 16);
        float h1 = av1 + __shfl_xor(av1, 8); h1 += __shfl_xor(h1, 16);
        float h2 = av2 + __shfl_xor(av2, 8); h2 += __shfl_xor(h2, 16);
        float h3 = av3 + __shfl_xor(av3, 8); h3 += __shfl_xor(h3, 16);
        float h4 = av4 + __shfl_xor(av4, 8); h4 += __shfl_xor(h4, 16);
        float h5 = av5 + __shfl_xor(av5, 8); h5 += __shfl_xor(h5, 16);
        float h6 = av6 + __shfl_xor(av6, 8); h6 += __shfl_xor(h6, 16);
        float h7 = av7 + __shfl_xor(av7, 8); h7 += __shfl_xor(h7, 16);
        if (half == 0 && cl < 8) {
            int c = cl * 8;
            float4 o0, o1;
            o0.x = 0.25f * h0 + bias[c + 0]; o0.y = 0.25f * h1 + bias[c + 1];
            o0.z = 0.25f * h2 + bias[c + 2]; o0.w = 0.25f * h3 + bias[c + 3];
            o1.x = 0.25f * h4 + bias[c + 4]; o1.y = 0.25f * h5 + bias[c + 5];
            o1.z = 0.25f * h6 + bias[c + 6]; o1.w = 0.25f * h7 + bias[c + 7];
            *reinterpret_cast<float4*>(out + (size_t)d * HID + c) = o0;
            *reinterpret_cast<float4*>(out + (size_t)d * HID + c + 4) = o1;
        }
    }
}

// ---------------- BatchNorm ----------------

__global__ void bn_stats(const float* __restrict__ x, float* colsum, float* colsq, int n) {
    int col = threadIdx.x;  // 256 threads
    float s = 0.f, q = 0.f;
    for (int r = blockIdx.x; r < n; r += gridDim.x) {
        float v = x[(size_t)r * HC + col];
        s += v;
        q += v * v;
    }
    atomicAdd(&colsum[col], s);
    atomicAdd(&colsq[col], q);
}

__global__ void bn_finalize(const float* colsum, const float* colsq,
                            const float* __restrict__ g, const float* __restrict__ be,
                            float* scale, float* shift, int n) {
    int col = threadIdx.x;  // 256
    float mu = colsum[col] / (float)n;
    float var = colsq[col] / (float)n - mu * mu;
    float sc = g[col] * rsqrtf(var + BN_EPS);
    scale[col] = sc;
    shift[col] = be[col] - mu * sc;
}

__global__ void bn_apply_elu(const float* __restrict__ x,
                             const float* __restrict__ scale, const float* __restrict__ shift,
                             float* __restrict__ xs_out, bf16s* __restrict__ act, int n) {
    int col = threadIdx.x;  // 256
    float sc = scale[col], sh = shift[col];
    for (int r = blockIdx.x; r < n; r += gridDim.x) {
        float v = x[(size_t)r * HC + col];
        float y = v * sc + sh;
        xs_out[(size_t)r * HC + col] = y;
        float e = y > 0.f ? y : __expf(y) - 1.f;
        act[(size_t)r * HC + col] = f2bs(e);
    }
}

// ---------------- pool (no atomics) + final linear ----------------

__global__ void pool_graphs(const float* __restrict__ xs2, const int* __restrict__ gstart,
                            float* __restrict__ pooled) {
    int g = blockIdx.x * (blockDim.x >> 6) + (threadIdx.x >> 6);
    int lane = threadIdx.x & 63;
    if (g >= NUM_GRAPHS) return;
    int a = gstart[g], b = gstart[g + 1];
    float acc = 0.f;
    for (int n = a; n < b; n++) acc += xs2[(size_t)n * HID + lane];
    pooled[g * HID + lane] = acc / fmaxf((float)(b - a), 1.f);
}

__global__ void final_linear(const float* __restrict__ pooled, const float* __restrict__ Wlin,
                             const float* __restrict__ blin, float* __restrict__ out) {
    int tid = blockIdx.x * blockDim.x + threadIdx.x;
    if (tid >= NUM_GRAPHS * OUT_DIM) return;
    int g = tid / OUT_DIM, o = tid % OUT_DIM;
    float s = blin[o];
    for (int c = 0; c < HID; ++c) s += pooled[g * HID + c] * Wlin[c * OUT_DIM + o];
    out[g * OUT_DIM + o] = s;
}

// ---------------- host side ----------------

extern "C" void kernel_launch(void* const* d_in, const int* in_sizes, int n_in,
                              void* d_out, int out_size, void* d_ws, size_t ws_size,
                              hipStream_t stream) {
    const float* x     = (const float*)d_in[0];
    const int*   ei    = (const int*)d_in[1];   // [2,E]
    const int*   batch = (const int*)d_in[2];
    const float* W1  = (const float*)d_in[3];
    const float* as1 = (const float*)d_in[4];
    const float* ad1 = (const float*)d_in[5];
    const float* b1  = (const float*)d_in[6];
    const float* g1  = (const float*)d_in[7];
    const float* be1 = (const float*)d_in[8];
    const float* W2  = (const float*)d_in[9];
    const float* as2 = (const float*)d_in[10];
    const float* ad2 = (const float*)d_in[11];
    const float* b2  = (const float*)d_in[12];
    const float* g2  = (const float*)d_in[13];
    const float* be2 = (const float*)d_in[14];
    const float* W3  = (const float*)d_in[15];
    const float* as3 = (const float*)d_in[16];
    const float* ad3 = (const float*)d_in[17];
    const float* b3  = (const float*)d_in[18];
    const float* Wlin = (const float*)d_in[19];
    const float* blin = (const float*)d_in[20];

    // output regions
    float* out_final = (float*)d_out;                 // [128,10]
    float* xs0 = out_final + NUM_GRAPHS * OUT_DIM;    // [N,256]
    float* xs1 = xs0 + (size_t)N_NODES * HC;          // [N,256]
    float* xs2 = xs1 + (size_t)N_NODES * HC;          // [N,64]
    float* pooled_out = xs2 + (size_t)N_NODES * HID;  // [128,64]

    // workspace carve
    char* p = (char*)d_ws;
    auto alloc = [&](size_t bytes) { char* r = p; p += (bytes + 255) & ~(size_t)255; return (void*)r; };
    bf16s* hfeat  = (bf16s*)alloc((size_t)N_NODES * HC * 2);
    bf16s* actC   = (bf16s*)alloc((size_t)N_NODES * HC * 2);
    bf16s* xb     = (bf16s*)alloc((size_t)N_NODES * F_IN * 2);
    float* gatB   = (float*)alloc((size_t)N_NODES * HC * 4);
    bf16s* Wt1    = (bf16s*)alloc((size_t)HC * F_IN * 2);
    bf16s* Wt2    = (bf16s*)alloc((size_t)HC * HC * 2);
    bf16s* Wt3    = (bf16s*)alloc((size_t)HC * HC * 2);
    float* asb    = (float*)alloc((size_t)N_NODES * HEADS * 4);
    float* adb    = (float*)alloc((size_t)N_NODES * HEADS * 4);
    int*   deg    = (int*)alloc((size_t)N_NODES * 4);
    int*   rowptr = (int*)alloc((size_t)(N_NODES + 1) * 4);
    int*   esrc   = (int*)alloc((size_t)(N_EDGES + N_NODES) * 4);
    float* colstats = (float*)alloc(2 * HC * 4);
    float* colsum = colstats;
    float* colsq  = colstats + HC;
    float* scale  = (float*)alloc(HC * 4);
    float* shift  = (float*)alloc(HC * 4);
    int*   gstart = (int*)alloc((NUM_GRAPHS + 1) * 4);

    const int ETOT = N_EDGES + N_NODES;

    // ---- CSR build (once, reused for all 3 layers) ----
    fill_i32<<<(N_NODES + 255) / 256, 256, 0, stream>>>(deg, N_NODES, 1);  // self-loop
    count_deg<<<(N_EDGES + 255) / 256, 256, 0, stream>>>(ei + N_EDGES, deg, N_EDGES);
    scan_deg<<<1, 1024, 0, stream>>>(deg, rowptr, N_NODES);
    copy_i32<<<(N_NODES + 255) / 256, 256, 0, stream>>>(deg, rowptr, N_NODES);
    fill_csr<<<(ETOT + 255) / 256, 256, 0, stream>>>(ei, deg, esrc, N_EDGES, N_NODES);
    graph_bounds<<<1, 1024, 0, stream>>>(batch, gstart);

    // ---- weight prep ----
    conv_bf16<<<((N_NODES * F_IN / 4) + 255) / 256, 256, 0, stream>>>(x, xb, N_NODES * F_IN / 4);
    transpose_w<<<(HC * F_IN + 255) / 256, 256, 0, stream>>>(W1, Wt1, F_IN);
    transpose_w<<<(HC * HC + 255) / 256, 256, 0, stream>>>(W2, Wt2, HC);
    transpose_w<<<(HC * HC + 255) / 256, 256, 0, stream>>>(W3, Wt3, HC);

    int agg_blocks = N_NODES / 4;   // exactly 4 waves/block
    dim3 ggrid((N_NODES + 127) / 128, HEADS);

    // ---- layer 1 ----
    {
        gemm_bf16<<<ggrid, 256, 0, stream>>>(xb, Wt1, hfeat, as1, ad1, asb, adb, N_NODES, F_IN);
        gat_aggregate<0><<<agg_blocks, 256, 0, stream>>>(hfeat, asb, adb, rowptr, esrc, b1, gatB);
        fill_f32<<<2, 256, 0, stream>>>(colstats, 2 * HC, 0.f);
        bn_stats<<<512, 256, 0, stream>>>(gatB, colsum, colsq, N_NODES);
        bn_finalize<<<1, 256, 0, stream>>>(colsum, colsq, g1, be1, scale, shift, N_NODES);
        bn_apply_elu<<<2048, 256, 0, stream>>>(gatB, scale, shift, xs0, actC, N_NODES);
    }
    // ---- layer 2 ----
    {
        gemm_bf16<<<ggrid, 256, 0, stream>>>(actC, Wt2, hfeat, as2, ad2, asb, adb, N_NODES, HC);
        gat_aggregate<0><<<agg_blocks, 256, 0, stream>>>(hfeat, asb, adb, rowptr, esrc, b2, gatB);
        fill_f32<<<2, 256, 0, stream>>>(colstats, 2 * HC, 0.f);
        bn_stats<<<512, 256, 0, stream>>>(gatB, colsum, colsq, N_NODES);
        bn_finalize<<<1, 256, 0, stream>>>(colsum, colsq, g2, be2, scale, shift, N_NODES);
        bn_apply_elu<<<2048, 256, 0, stream>>>(gatB, scale, shift, xs1, actC, N_NODES);
    }
    // ---- layer 3 ----
    {
        gemm_bf16<<<ggrid, 256, 0, stream>>>(actC, Wt3, hfeat, as3, ad3, asb, adb, N_NODES, HC);
        gat_aggregate<1><<<agg_blocks, 256, 0, stream>>>(hfeat, asb, adb, rowptr, esrc, b3, xs2);
    }
    // ---- pool + final linear ----
    pool_graphs<<<NUM_GRAPHS / 4, 256, 0, stream>>>(xs2, gstart, pooled_out);
    final_linear<<<(NUM_GRAPHS * OUT_DIM + 255) / 256, 256, 0, stream>>>(pooled_out, Wlin, blin, out_final);
}

// Round 5
// 425.868 us; speedup vs baseline: 1.4435x; 1.1392x over previous
//
#include <hip/hip_runtime.h>
#include <hip/hip_bf16.h>
#include <math.h>

#define N_NODES 20000
#define N_EDGES 640000
#define F_IN 128
#define HID 64
#define HEADS 4
#define HC 256      // HEADS*HID
#define OUT_DIM 10
#define NUM_GRAPHS 128
#define NEG_SLOPE 0.2f
#define BN_EPS 1e-5f

typedef short bf16s;
using bf16x8 = __attribute__((ext_vector_type(8))) short;
using bf16x4 = __attribute__((ext_vector_type(4))) short;
using f32x4 = __attribute__((ext_vector_type(4))) float;

__device__ __forceinline__ float bs2f(short s) {
    unsigned int u = ((unsigned int)(unsigned short)s) << 16;
    return __builtin_bit_cast(float, u);
}
__device__ __forceinline__ short f2bs(float f) {
    unsigned int u = __builtin_bit_cast(unsigned int, f);
    unsigned int r = u + 0x7FFFu + ((u >> 16) & 1u);
    return (short)(r >> 16);
}

// ---------------- utility kernels ----------------

__global__ void fill_i32(int* p, int n, int val) {
    int tid = blockIdx.x * blockDim.x + threadIdx.x;
    if (tid < n) p[tid] = val;
}

__global__ void fill_f32(float* p, int n, float val) {
    int tid = blockIdx.x * blockDim.x + threadIdx.x;
    if (tid < n) p[tid] = val;
}

__global__ void conv_bf16(const float* __restrict__ in, bf16s* __restrict__ out, int n4) {
    int tid = blockIdx.x * blockDim.x + threadIdx.x;
    if (tid >= n4) return;
    float4 v = reinterpret_cast<const float4*>(in)[tid];
    bf16x4 o;
    o[0] = f2bs(v.x); o[1] = f2bs(v.y); o[2] = f2bs(v.z); o[3] = f2bs(v.w);
    reinterpret_cast<bf16x4*>(out)[tid] = o;
}

// all three W transposes in one kernel: W [K][256] fp32 -> Wt [256][K] bf16
__global__ void prep_weights(const float* __restrict__ W1, const float* __restrict__ W2,
                             const float* __restrict__ W3,
                             bf16s* __restrict__ Wt1, bf16s* __restrict__ Wt2,
                             bf16s* __restrict__ Wt3) {
    int tid = blockIdx.x * blockDim.x + threadIdx.x;
    if (tid < HC * F_IN) {
        int c = tid >> 7, k = tid & (F_IN - 1);
        Wt1[tid] = f2bs(W1[(size_t)k * HC + c]);
    } else if (tid < HC * F_IN + HC * HC) {
        int t = tid - HC * F_IN;
        int c = t >> 8, k = t & (HC - 1);
        Wt2[t] = f2bs(W2[(size_t)k * HC + c]);
    } else if (tid < HC * F_IN + 2 * HC * HC) {
        int t = tid - HC * F_IN - HC * HC;
        int c = t >> 8, k = t & (HC - 1);
        Wt3[t] = f2bs(W3[(size_t)k * HC + c]);
    }
}

// ---------------- CSR build ----------------

__global__ void count_deg(const int* __restrict__ ei_dst, int* deg, int E) {
    int tid = blockIdx.x * blockDim.x + threadIdx.x;
    if (tid < E) atomicAdd(&deg[ei_dst[tid]], 1);
}

// single-block scan, shfl-based: rowptr[i+1] = incl_prefix(deg)[i]; cursor[i] = excl prefix
__global__ void scan_deg(const int* __restrict__ deg, int* __restrict__ rowptr,
                         int* __restrict__ cursor, int n) {
    __shared__ int wsum[16];
    __shared__ int carry_s;
    int tid = threadIdx.x;          // 1024 threads
    int wid = tid >> 6, lane = tid & 63;
    if (tid == 0) { carry_s = 0; rowptr[0] = 0; }
    __syncthreads();
    for (int base = 0; base < n; base += 1024) {
        int i = base + tid;
        int v = (i < n) ? deg[i] : 0;
        int x = v;
        #pragma unroll
        for (int off = 1; off < 64; off <<= 1) {
            int t = __shfl_up(x, off);
            if (lane >= off) x += t;
        }
        if (lane == 63) wsum[wid] = x;
        __syncthreads();
        if (tid == 0) {
            int acc = carry_s;
            #pragma unroll
            for (int w = 0; w < 16; w++) { int t = wsum[w]; wsum[w] = acc; acc += t; }
            carry_s = acc;
        }
        __syncthreads();
        int inc = x + wsum[wid];
        if (i < n) { rowptr[i + 1] = inc; cursor[i] = inc - v; }
        __syncthreads();
    }
}

__global__ void fill_csr(const int* __restrict__ ei, int* cursor, int* esrc, int E, int n) {
    int tid = blockIdx.x * blockDim.x + threadIdx.x;
    if (tid < E) {
        int src = ei[tid];
        int dst = ei[E + tid];
        int pos = atomicAdd(&cursor[dst], 1);
        esrc[pos] = src;
    } else if (tid < E + n) {
        int node = tid - E;
        int pos = atomicAdd(&cursor[node], 1);
        esrc[pos] = node;
    }
}

// graph boundaries from sorted batch via binary search
__global__ void graph_bounds(const int* __restrict__ batch, int* __restrict__ gstart) {
    int g = threadIdx.x;
    if (g > NUM_GRAPHS) return;
    int lo = 0, hi = N_NODES;
    while (lo < hi) {
        int mid = (lo + hi) >> 1;
        if (batch[mid] < g) lo = mid + 1; else hi = mid;
    }
    gstart[g] = lo;
}

// ---------------- bf16 MFMA GEMM + fused attention coefficients ----------------
// H[M,256] = A[M,K] @ Wt^T; blockIdx.y == head; epilogue computes asb/adb.

__global__ __launch_bounds__(256) void gemm_bf16(
        const bf16s* __restrict__ A, const bf16s* __restrict__ Wt,
        bf16s* __restrict__ Hout,
        const float* __restrict__ a_src, const float* __restrict__ a_dst,
        float* __restrict__ asb, float* __restrict__ adb,
        int M, int K) {
    __shared__ bf16s As[128][72];
    __shared__ bf16s Bs[64][72];
    int tid = threadIdx.x;
    int wave = tid >> 6, lane = tid & 63;
    int row0 = blockIdx.x * 128;
    int head = blockIdx.y;
    int col0 = head * 64;
    int lr = lane & 15, lk = lane >> 4;

    f32x4 acc[2][4];
    #pragma unroll
    for (int i = 0; i < 2; i++)
        #pragma unroll
        for (int j = 0; j < 4; j++)
            acc[i][j] = (f32x4){0.f, 0.f, 0.f, 0.f};

    for (int k0 = 0; k0 < K; k0 += 64) {
        #pragma unroll
        for (int i = 0; i < 4; i++) {
            int idx = tid + i * 256;
            int r = idx >> 3, ch = idx & 7;
            int gr = row0 + r;
            bf16x8 v = {};
            if (gr < M) v = *reinterpret_cast<const bf16x8*>(A + (size_t)gr * K + k0 + ch * 8);
            *reinterpret_cast<bf16x8*>(&As[r][ch * 8]) = v;
        }
        #pragma unroll
        for (int i = 0; i < 2; i++) {
            int idx = tid + i * 256;
            int r = idx >> 3, ch = idx & 7;
            bf16x8 v = *reinterpret_cast<const bf16x8*>(Wt + (size_t)(col0 + r) * K + k0 + ch * 8);
            *reinterpret_cast<bf16x8*>(&Bs[r][ch * 8]) = v;
        }
        __syncthreads();
        #pragma unroll
        for (int ks = 0; ks < 2; ks++) {
            bf16x8 bfr[4];
            #pragma unroll
            for (int j = 0; j < 4; j++)
                bfr[j] = *reinterpret_cast<const bf16x8*>(&Bs[j * 16 + lr][ks * 32 + lk * 8]);
            #pragma unroll
            for (int i = 0; i < 2; i++) {
                bf16x8 afr = *reinterpret_cast<const bf16x8*>(&As[wave * 32 + i * 16 + lr][ks * 32 + lk * 8]);
                #pragma unroll
                for (int j = 0; j < 4; j++)
                    acc[i][j] = __builtin_amdgcn_mfma_f32_16x16x32_bf16(afr, bfr[j], acc[i][j], 0, 0, 0);
            }
        }
        __syncthreads();
    }

    // store H (C/D layout: col = lane&15, row = (lane>>4)*4 + q)
    #pragma unroll
    for (int i = 0; i < 2; i++) {
        #pragma unroll
        for (int q = 0; q < 4; q++) {
            int r = row0 + wave * 32 + i * 16 + lk * 4 + q;
            if (r < M) {
                #pragma unroll
                for (int j = 0; j < 4; j++) {
                    int c = col0 + j * 16 + lr;
                    Hout[(size_t)r * HC + c] = f2bs(acc[i][j][q]);
                }
            }
        }
    }

    // fused attn coefficients: per-row dot with a_src/a_dst for this head
    float asv0 = a_src[col0 + 0 * 16 + lr], asv1 = a_src[col0 + 1 * 16 + lr];
    float asv2 = a_src[col0 + 2 * 16 + lr], asv3 = a_src[col0 + 3 * 16 + lr];
    float adv0 = a_dst[col0 + 0 * 16 + lr], adv1 = a_dst[col0 + 1 * 16 + lr];
    float adv2 = a_dst[col0 + 2 * 16 + lr], adv3 = a_dst[col0 + 3 * 16 + lr];
    #pragma unroll
    for (int i = 0; i < 2; i++) {
        #pragma unroll
        for (int q = 0; q < 4; q++) {
            float ps = acc[i][0][q] * asv0 + acc[i][1][q] * asv1 + acc[i][2][q] * asv2 + acc[i][3][q] * asv3;
            float pd = acc[i][0][q] * adv0 + acc[i][1][q] * adv1 + acc[i][2][q] * adv2 + acc[i][3][q] * adv3;
            #pragma unroll
            for (int off = 1; off < 16; off <<= 1) {
                ps += __shfl_xor(ps, off);
                pd += __shfl_xor(pd, off);
            }
            int r = row0 + wave * 32 + i * 16 + lk * 4 + q;
            if (lr == 0 && r < M) {
                asb[r * HEADS + head] = ps;
                adb[r * HEADS + head] = pd;
            }
        }
    }
}

// ---------------- GAT aggregation v2 ----------------
// No max-shift (e = lrelu(as+ad) is O(1) here: exp safe; softmax identical up to rounding).
// Pass A: sum of exp per head, stashing exp(e) per edge in LDS (deg<=128; fallback recompute).
// Pass B: weighted gather, alpha = stash * 1/sum.

__device__ __forceinline__ float lrelu(float x) { return x > 0.f ? x : NEG_SLOPE * x; }

// MODE 0: write out [N,HC] fp32 (+bias)
// MODE 1: head-mean + b3 -> write xs2 [N,HID]
template<int MODE>
__global__ __launch_bounds__(256) void gat_aggregate(
        const bf16s* __restrict__ hfeat,
        const float* __restrict__ asb, const float* __restrict__ adb,
        const int* __restrict__ rowptr, const int* __restrict__ esrc,
        const float* __restrict__ bias,
        float* __restrict__ out) {
    __shared__ float4 exps[4][128];   // 8 KB: per-wave exp(e) stash
    int wid = threadIdx.x >> 6, lane = threadIdx.x & 63;
    int d = blockIdx.x * 4 + wid;     // grid exact: 4 waves/block
    int start = rowptr[d], end = rowptr[d + 1];
    int deg = end - start;

    float adv0 = adb[d * HEADS + 0], adv1 = adb[d * HEADS + 1];
    float adv2 = adb[d * HEADS + 2], adv3 = adb[d * HEADS + 3];

    // ---- pass A: per-head sum of exp(e); stash exp(e) in LDS ----
    float s0 = 0.f, s1 = 0.f, s2 = 0.f, s3 = 0.f;
    for (int j = start + lane; j < end; j += 64) {
        int s = esrc[j];
        const float4 av = *reinterpret_cast<const float4*>(asb + (size_t)s * HEADS);
        float e0 = __expf(lrelu(av.x + adv0));
        float e1 = __expf(lrelu(av.y + adv1));
        float e2 = __expf(lrelu(av.z + adv2));
        float e3 = __expf(lrelu(av.w + adv3));
        int idx = j - start;
        if (idx < 128) {
            float4 ev; ev.x = e0; ev.y = e1; ev.z = e2; ev.w = e3;
            exps[wid][idx] = ev;
        }
        s0 += e0; s1 += e1; s2 += e2; s3 += e3;
    }
    #pragma unroll
    for (int off = 32; off > 0; off >>= 1) {
        s0 += __shfl_xor(s0, off);
        s1 += __shfl_xor(s1, off);
        s2 += __shfl_xor(s2, off);
        s3 += __shfl_xor(s3, off);
    }
    float r0 = 1.f / (s0 + 1e-16f), r1 = 1.f / (s1 + 1e-16f);
    float r2 = 1.f / (s2 + 1e-16f), r3 = 1.f / (s3 + 1e-16f);

    // ---- pass B: weighted gather; 2 edges/iter (half-wave each); lane owns 8 cols ----
    int half = lane >> 5;
    int cl = lane & 31;
    int hsel = cl >> 3;
    float rdh = (hsel == 0) ? r0 : (hsel == 1) ? r1 : (hsel == 2) ? r2 : r3;
    float adh = (hsel == 0) ? adv0 : (hsel == 1) ? adv1 : (hsel == 2) ? adv2 : adv3;

    float av0 = 0.f, av1 = 0.f, av2 = 0.f, av3 = 0.f;
    float av4 = 0.f, av5 = 0.f, av6 = 0.f, av7 = 0.f;
    int nfull = deg & ~1;
    for (int j = 0; j < nfull; j += 2) {
        int idx = j + half;
        int s = esrc[start + idx];
        float al;
        if (idx < 128) {
            al = reinterpret_cast<const float*>(&exps[wid][idx])[hsel] * rdh;
        } else {
            al = __expf(lrelu(asb[(size_t)s * HEADS + hsel] + adh)) * rdh;
        }
        const bf16x8 v = *reinterpret_cast<const bf16x8*>(hfeat + (size_t)s * HC + cl * 8);
        av0 += al * bs2f(v[0]); av1 += al * bs2f(v[1]);
        av2 += al * bs2f(v[2]); av3 += al * bs2f(v[3]);
        av4 += al * bs2f(v[4]); av5 += al * bs2f(v[5]);
        av6 += al * bs2f(v[6]); av7 += al * bs2f(v[7]);
    }
    if ((deg & 1) && half == 0) {   // odd tail: half 0 only
        int idx = nfull;
        int s = esrc[start + idx];
        float al;
        if (idx < 128) {
            al = reinterpret_cast<const float*>(&exps[wid][idx])[hsel] * rdh;
        } else {
            al = __expf(lrelu(asb[(size_t)s * HEADS + hsel] + adh)) * rdh;
        }
        const bf16x8 v = *reinterpret_cast<const bf16x8*>(hfeat + (size_t)s * HC + cl * 8);
        av0 += al * bs2f(v[0]); av1 += al * bs2f(v[1]);
        av2 += al * bs2f(v[2]); av3 += al * bs2f(v[3]);
        av4 += al * bs2f(v[4]); av5 += al * bs2f(v[5]);
        av6 += al * bs2f(v[6]); av7 += al * bs2f(v[7]);
    }
    av0 += __shfl_xor(av0, 32); av1 += __shfl_xor(av1, 32);
    av2 += __shfl_xor(av2, 32); av3 += __shfl_xor(av3, 32);
    av4 += __shfl_xor(av4, 32); av5 += __shfl_xor(av5, 32);
    av6 += __shfl_xor(av6, 32); av7 += __shfl_xor(av7, 32);

    if constexpr (MODE == 0) {
        if (half == 0) {
            const float4 b0 = *reinterpret_cast<const float4*>(bias + cl * 8);
            const float4 b1 = *reinterpret_cast<const float4*>(bias + cl * 8 + 4);
            av0 += b0.x; av1 += b0.y; av2 += b0.z; av3 += b0.w;
            av4 += b1.x; av5 += b1.y; av6 += b1.z; av7 += b1.w;
            float4 o0; o0.x = av0; o0.y = av1; o0.z = av2; o0.w = av3;
            float4 o1; o1.x = av4; o1.y = av5; o1.z = av6; o1.w = av7;
            *reinterpret_cast<float4*>(out + (size_t)d * HC + cl * 8) = o0;
            *reinterpret_cast<float4*>(out + (size_t)d * HC + cl * 8 + 4) = o1;
        }
    } else {
        float h0 = av0 + __shfl_xor(av0, 8); h0 += __shfl_xor(h0, 16);
        float h1 = av1 + __shfl_xor(av1, 8); h1 += __shfl_xor(h1, 16);
        float h2 = av2 + __shfl_xor(av2, 8); h2 += __shfl_xor(h2, 16);
        float h3 = av3 + __shfl_xor(av3, 8); h3 += __shfl_xor(h3, 16);
        float h4 = av4 + __shfl_xor(av4, 8); h4 += __shfl_xor(h4, 16);
        float h5 = av5 + __shfl_xor(av5, 8); h5 += __shfl_xor(h5, 16);
        float h6 = av6 + __shfl_xor(av6, 8); h6 += __shfl_xor(h6, 16);
        float h7 = av7 + __shfl_xor(av7, 8); h7 += __shfl_xor(h7, 16);
        if (half == 0 && cl < 8) {
            int c = cl * 8;
            float4 o0, o1;
            o0.x = 0.25f * h0 + bias[c + 0]; o0.y = 0.25f * h1 + bias[c + 1];
            o0.z = 0.25f * h2 + bias[c + 2]; o0.w = 0.25f * h3 + bias[c + 3];
            o1.x = 0.25f * h4 + bias[c + 4]; o1.y = 0.25f * h5 + bias[c + 5];
            o1.z = 0.25f * h6 + bias[c + 6]; o1.w = 0.25f * h7 + bias[c + 7];
            *reinterpret_cast<float4*>(out + (size_t)d * HID + c) = o0;
            *reinterpret_cast<float4*>(out + (size_t)d * HID + c + 4) = o1;
        }
    }
}

// ---------------- BatchNorm ----------------

__global__ void bn_stats(const float* __restrict__ x, float* colsum, float* colsq, int n) {
    int col = threadIdx.x;  // 256 threads
    float s = 0.f, q = 0.f;
    for (int r = blockIdx.x; r < n; r += gridDim.x) {
        float v = x[(size_t)r * HC + col];
        s += v;
        q += v * v;
    }
    atomicAdd(&colsum[col], s);
    atomicAdd(&colsq[col], q);
}

// computes scale/shift, then zeroes colstats for the next user
__global__ void bn_finalize(float* colsum, float* colsq,
                            const float* __restrict__ g, const float* __restrict__ be,
                            float* scale, float* shift, int n) {
    int col = threadIdx.x;  // 256
    float mu = colsum[col] / (float)n;
    float var = colsq[col] / (float)n - mu * mu;
    float sc = g[col] * rsqrtf(var + BN_EPS);
    scale[col] = sc;
    shift[col] = be[col] - mu * sc;
    colsum[col] = 0.f;
    colsq[col] = 0.f;
}

__global__ void bn_apply_elu(const float* __restrict__ x,
                             const float* __restrict__ scale, const float* __restrict__ shift,
                             float* __restrict__ xs_out, bf16s* __restrict__ act, int n) {
    int col = threadIdx.x;  // 256
    float sc = scale[col], sh = shift[col];
    for (int r = blockIdx.x; r < n; r += gridDim.x) {
        float v = x[(size_t)r * HC + col];
        float y = v * sc + sh;
        xs_out[(size_t)r * HC + col] = y;
        float e = y > 0.f ? y : __expf(y) - 1.f;
        act[(size_t)r * HC + col] = f2bs(e);
    }
}

// ---------------- pool + final linear (merged) ----------------

__global__ void pool_final(const float* __restrict__ xs2, const int* __restrict__ gstart,
                           const float* __restrict__ Wlin, const float* __restrict__ blin,
                           float* __restrict__ pooled_out, float* __restrict__ out_final) {
    int g = blockIdx.x * 4 + (threadIdx.x >> 6);   // 32 blocks x 4 waves = 128 graphs
    int lane = threadIdx.x & 63;
    int a = gstart[g], b = gstart[g + 1];
    float acc = 0.f;
    for (int n = a; n < b; n++) acc += xs2[(size_t)n * HID + lane];
    float pooled = acc / fmaxf((float)(b - a), 1.f);
    pooled_out[g * HID + lane] = pooled;
    #pragma unroll
    for (int o = 0; o < OUT_DIM; o++) {
        float p = pooled * Wlin[lane * OUT_DIM + o];
        #pragma unroll
        for (int off = 32; off > 0; off >>= 1) p += __shfl_xor(p, off);
        if (lane == 0) out_final[g * OUT_DIM + o] = p + blin[o];
    }
}

// ---------------- host side ----------------

extern "C" void kernel_launch(void* const* d_in, const int* in_sizes, int n_in,
                              void* d_out, int out_size, void* d_ws, size_t ws_size,
                              hipStream_t stream) {
    const float* x     = (const float*)d_in[0];
    const int*   ei    = (const int*)d_in[1];   // [2,E]
    const int*   batch = (const int*)d_in[2];
    const float* W1  = (const float*)d_in[3];
    const float* as1 = (const float*)d_in[4];
    const float* ad1 = (const float*)d_in[5];
    const float* b1  = (const float*)d_in[6];
    const float* g1  = (const float*)d_in[7];
    const float* be1 = (const float*)d_in[8];
    const float* W2  = (const float*)d_in[9];
    const float* as2 = (const float*)d_in[10];
    const float* ad2 = (const float*)d_in[11];
    const float* b2  = (const float*)d_in[12];
    const float* g2  = (const float*)d_in[13];
    const float* be2 = (const float*)d_in[14];
    const float* W3  = (const float*)d_in[15];
    const float* as3 = (const float*)d_in[16];
    const float* ad3 = (const float*)d_in[17];
    const float* b3  = (const float*)d_in[18];
    const float* Wlin = (const float*)d_in[19];
    const float* blin = (const float*)d_in[20];

    // output regions
    float* out_final = (float*)d_out;                 // [128,10]
    float* xs0 = out_final + NUM_GRAPHS * OUT_DIM;    // [N,256]
    float* xs1 = xs0 + (size_t)N_NODES * HC;          // [N,256]
    float* xs2 = xs1 + (size_t)N_NODES * HC;          // [N,64]
    float* pooled_out = xs2 + (size_t)N_NODES * HID;  // [128,64]

    // workspace carve
    char* p = (char*)d_ws;
    auto alloc = [&](size_t bytes) { char* r = p; p += (bytes + 255) & ~(size_t)255; return (void*)r; };
    bf16s* hfeat  = (bf16s*)alloc((size_t)N_NODES * HC * 2);
    bf16s* actC   = (bf16s*)alloc((size_t)N_NODES * HC * 2);
    bf16s* xb     = (bf16s*)alloc((size_t)N_NODES * F_IN * 2);
    float* gatB   = (float*)alloc((size_t)N_NODES * HC * 4);
    bf16s* Wt1    = (bf16s*)alloc((size_t)HC * F_IN * 2);
    bf16s* Wt2    = (bf16s*)alloc((size_t)HC * HC * 2);
    bf16s* Wt3    = (bf16s*)alloc((size_t)HC * HC * 2);
    float* asb    = (float*)alloc((size_t)N_NODES * HEADS * 4);
    float* adb    = (float*)alloc((size_t)N_NODES * HEADS * 4);
    int*   deg    = (int*)alloc((size_t)N_NODES * 4);
    int*   cursor = (int*)alloc((size_t)N_NODES * 4);
    int*   rowptr = (int*)alloc((size_t)(N_NODES + 1) * 4);
    int*   esrc   = (int*)alloc((size_t)(N_EDGES + N_NODES) * 4);
    float* colstats = (float*)alloc(2 * HC * 4);
    float* colsum = colstats;
    float* colsq  = colstats + HC;
    float* scale  = (float*)alloc(HC * 4);
    float* shift  = (float*)alloc(HC * 4);
    int*   gstart = (int*)alloc((NUM_GRAPHS + 1) * 4);

    const int ETOT = N_EDGES + N_NODES;

    // ---- CSR build (once, reused for all 3 layers) ----
    fill_i32<<<(N_NODES + 255) / 256, 256, 0, stream>>>(deg, N_NODES, 1);  // self-loop
    count_deg<<<(N_EDGES + 255) / 256, 256, 0, stream>>>(ei + N_EDGES, deg, N_EDGES);
    scan_deg<<<1, 1024, 0, stream>>>(deg, rowptr, cursor, N_NODES);
    fill_csr<<<(ETOT + 255) / 256, 256, 0, stream>>>(ei, cursor, esrc, N_EDGES, N_NODES);
    graph_bounds<<<1, 256, 0, stream>>>(batch, gstart);

    // ---- input/weight prep ----
    conv_bf16<<<((N_NODES * F_IN / 4) + 255) / 256, 256, 0, stream>>>(x, xb, N_NODES * F_IN / 4);
    prep_weights<<<(HC * F_IN + 2 * HC * HC + 255) / 256, 256, 0, stream>>>(W1, W2, W3, Wt1, Wt2, Wt3);
    fill_f32<<<2, 256, 0, stream>>>(colstats, 2 * HC, 0.f);

    int agg_blocks = N_NODES / 4;   // exactly 4 waves/block
    dim3 ggrid((N_NODES + 127) / 128, HEADS);

    // ---- layer 1 ----
    {
        gemm_bf16<<<ggrid, 256, 0, stream>>>(xb, Wt1, hfeat, as1, ad1, asb, adb, N_NODES, F_IN);
        gat_aggregate<0><<<agg_blocks, 256, 0, stream>>>(hfeat, asb, adb, rowptr, esrc, b1, gatB);
        bn_stats<<<512, 256, 0, stream>>>(gatB, colsum, colsq, N_NODES);
        bn_finalize<<<1, 256, 0, stream>>>(colsum, colsq, g1, be1, scale, shift, N_NODES);
        bn_apply_elu<<<2048, 256, 0, stream>>>(gatB, scale, shift, xs0, actC, N_NODES);
    }
    // ---- layer 2 ----
    {
        gemm_bf16<<<ggrid, 256, 0, stream>>>(actC, Wt2, hfeat, as2, ad2, asb, adb, N_NODES, HC);
        gat_aggregate<0><<<agg_blocks, 256, 0, stream>>>(hfeat, asb, adb, rowptr, esrc, b2, gatB);
        bn_stats<<<512, 256, 0, stream>>>(gatB, colsum, colsq, N_NODES);
        bn_finalize<<<1, 256, 0, stream>>>(colsum, colsq, g2, be2, scale, shift, N_NODES);
        bn_apply_elu<<<2048, 256, 0, stream>>>(gatB, scale, shift, xs1, actC, N_NODES);
    }
    // ---- layer 3 ----
    {
        gemm_bf16<<<ggrid, 256, 0, stream>>>(actC, Wt3, hfeat, as3, ad3, asb, adb, N_NODES, HC);
        gat_aggregate<1><<<agg_blocks, 256, 0, stream>>>(hfeat, asb, adb, rowptr, esrc, b3, xs2);
    }
    // ---- pool + final linear ----
    pool_final<<<NUM_GRAPHS / 4, 256, 0, stream>>>(xs2, gstart, Wlin, blin, pooled_out, out_final);
}

// Round 6
// 384.535 us; speedup vs baseline: 1.5987x; 1.1075x over previous
//
#include <hip/hip_runtime.h>
#include <hip/hip_bf16.h>
#include <math.h>

#define N_NODES 20000
#define N_EDGES 640000
#define F_IN 128
#define HID 64
#define HEADS 4
#define HC 256      // HEADS*HID
#define OUT_DIM 10
#define NUM_GRAPHS 128
#define NEG_SLOPE 0.2f
#define BN_EPS 1e-5f

typedef short bf16s;
using bf16x8 = __attribute__((ext_vector_type(8))) short;
using bf16x4 = __attribute__((ext_vector_type(4))) short;
using f32x4 = __attribute__((ext_vector_type(4))) float;

__device__ __forceinline__ float bs2f(short s) {
    unsigned int u = ((unsigned int)(unsigned short)s) << 16;
    return __builtin_bit_cast(float, u);
}
__device__ __forceinline__ short f2bs(float f) {
    unsigned int u = __builtin_bit_cast(unsigned int, f);
    unsigned int r = u + 0x7FFFu + ((u >> 16) & 1u);
    return (short)(r >> 16);
}

// ---------------- utility kernels ----------------

__global__ void fill_i32(int* p, int n, int val) {
    int tid = blockIdx.x * blockDim.x + threadIdx.x;
    if (tid < n) p[tid] = val;
}

__global__ void fill_f32(float* p, int n, float val) {
    int tid = blockIdx.x * blockDim.x + threadIdx.x;
    if (tid < n) p[tid] = val;
}

__global__ void conv_bf16(const float* __restrict__ in, bf16s* __restrict__ out, int n4) {
    int tid = blockIdx.x * blockDim.x + threadIdx.x;
    if (tid >= n4) return;
    float4 v = reinterpret_cast<const float4*>(in)[tid];
    bf16x4 o;
    o[0] = f2bs(v.x); o[1] = f2bs(v.y); o[2] = f2bs(v.z); o[3] = f2bs(v.w);
    reinterpret_cast<bf16x4*>(out)[tid] = o;
}

// all three W transposes in one kernel: W [K][256] fp32 -> Wt [256][K] bf16
__global__ void prep_weights(const float* __restrict__ W1, const float* __restrict__ W2,
                             const float* __restrict__ W3,
                             bf16s* __restrict__ Wt1, bf16s* __restrict__ Wt2,
                             bf16s* __restrict__ Wt3) {
    int tid = blockIdx.x * blockDim.x + threadIdx.x;
    if (tid < HC * F_IN) {
        int c = tid >> 7, k = tid & (F_IN - 1);
        Wt1[tid] = f2bs(W1[(size_t)k * HC + c]);
    } else if (tid < HC * F_IN + HC * HC) {
        int t = tid - HC * F_IN;
        int c = t >> 8, k = t & (HC - 1);
        Wt2[t] = f2bs(W2[(size_t)k * HC + c]);
    } else if (tid < HC * F_IN + 2 * HC * HC) {
        int t = tid - HC * F_IN - HC * HC;
        int c = t >> 8, k = t & (HC - 1);
        Wt3[t] = f2bs(W3[(size_t)k * HC + c]);
    }
}

// ---------------- CSR build ----------------

__global__ void count_deg(const int* __restrict__ ei_dst, int* deg, int E) {
    int tid = blockIdx.x * blockDim.x + threadIdx.x;
    if (tid < E) atomicAdd(&deg[ei_dst[tid]], 1);
}

// single-block scan, shfl-based: rowptr[i+1] = incl_prefix(deg)[i]; cursor[i] = excl prefix
__global__ void scan_deg(const int* __restrict__ deg, int* __restrict__ rowptr,
                         int* __restrict__ cursor, int n) {
    __shared__ int wsum[16];
    __shared__ int carry_s;
    int tid = threadIdx.x;          // 1024 threads
    int wid = tid >> 6, lane = tid & 63;
    if (tid == 0) { carry_s = 0; rowptr[0] = 0; }
    __syncthreads();
    for (int base = 0; base < n; base += 1024) {
        int i = base + tid;
        int v = (i < n) ? deg[i] : 0;
        int x = v;
        #pragma unroll
        for (int off = 1; off < 64; off <<= 1) {
            int t = __shfl_up(x, off);
            if (lane >= off) x += t;
        }
        if (lane == 63) wsum[wid] = x;
        __syncthreads();
        if (tid == 0) {
            int acc = carry_s;
            #pragma unroll
            for (int w = 0; w < 16; w++) { int t = wsum[w]; wsum[w] = acc; acc += t; }
            carry_s = acc;
        }
        __syncthreads();
        int inc = x + wsum[wid];
        if (i < n) { rowptr[i + 1] = inc; cursor[i] = inc - v; }
        __syncthreads();
    }
}

__global__ void fill_csr(const int* __restrict__ ei, int* cursor, int* esrc, int E, int n) {
    int tid = blockIdx.x * blockDim.x + threadIdx.x;
    if (tid < E) {
        int src = ei[tid];
        int dst = ei[E + tid];
        int pos = atomicAdd(&cursor[dst], 1);
        esrc[pos] = src;
    } else if (tid < E + n) {
        int node = tid - E;
        int pos = atomicAdd(&cursor[node], 1);
        esrc[pos] = node;
    }
}

// ---------------- bf16 MFMA GEMM + fused attention coefficients ----------------
// H[M,256] = A[M,K] @ Wt^T; blockIdx.y == head; epilogue computes asb/adb.

__global__ __launch_bounds__(256) void gemm_bf16(
        const bf16s* __restrict__ A, const bf16s* __restrict__ Wt,
        bf16s* __restrict__ Hout,
        const float* __restrict__ a_src, const float* __restrict__ a_dst,
        float* __restrict__ asb, float* __restrict__ adb,
        int M, int K) {
    __shared__ bf16s As[128][72];
    __shared__ bf16s Bs[64][72];
    int tid = threadIdx.x;
    int wave = tid >> 6, lane = tid & 63;
    int row0 = blockIdx.x * 128;
    int head = blockIdx.y;
    int col0 = head * 64;
    int lr = lane & 15, lk = lane >> 4;

    f32x4 acc[2][4];
    #pragma unroll
    for (int i = 0; i < 2; i++)
        #pragma unroll
        for (int j = 0; j < 4; j++)
            acc[i][j] = (f32x4){0.f, 0.f, 0.f, 0.f};

    for (int k0 = 0; k0 < K; k0 += 64) {
        #pragma unroll
        for (int i = 0; i < 4; i++) {
            int idx = tid + i * 256;
            int r = idx >> 3, ch = idx & 7;
            int gr = row0 + r;
            bf16x8 v = {};
            if (gr < M) v = *reinterpret_cast<const bf16x8*>(A + (size_t)gr * K + k0 + ch * 8);
            *reinterpret_cast<bf16x8*>(&As[r][ch * 8]) = v;
        }
        #pragma unroll
        for (int i = 0; i < 2; i++) {
            int idx = tid + i * 256;
            int r = idx >> 3, ch = idx & 7;
            bf16x8 v = *reinterpret_cast<const bf16x8*>(Wt + (size_t)(col0 + r) * K + k0 + ch * 8);
            *reinterpret_cast<bf16x8*>(&Bs[r][ch * 8]) = v;
        }
        __syncthreads();
        #pragma unroll
        for (int ks = 0; ks < 2; ks++) {
            bf16x8 bfr[4];
            #pragma unroll
            for (int j = 0; j < 4; j++)
                bfr[j] = *reinterpret_cast<const bf16x8*>(&Bs[j * 16 + lr][ks * 32 + lk * 8]);
            #pragma unroll
            for (int i = 0; i < 2; i++) {
                bf16x8 afr = *reinterpret_cast<const bf16x8*>(&As[wave * 32 + i * 16 + lr][ks * 32 + lk * 8]);
                #pragma unroll
                for (int j = 0; j < 4; j++)
                    acc[i][j] = __builtin_amdgcn_mfma_f32_16x16x32_bf16(afr, bfr[j], acc[i][j], 0, 0, 0);
            }
        }
        __syncthreads();
    }

    // store H (C/D layout: col = lane&15, row = (lane>>4)*4 + q)
    #pragma unroll
    for (int i = 0; i < 2; i++) {
        #pragma unroll
        for (int q = 0; q < 4; q++) {
            int r = row0 + wave * 32 + i * 16 + lk * 4 + q;
            if (r < M) {
                #pragma unroll
                for (int j = 0; j < 4; j++) {
                    int c = col0 + j * 16 + lr;
                    Hout[(size_t)r * HC + c] = f2bs(acc[i][j][q]);
                }
            }
        }
    }

    // fused attn coefficients: per-row dot with a_src/a_dst for this head
    float asv0 = a_src[col0 + 0 * 16 + lr], asv1 = a_src[col0 + 1 * 16 + lr];
    float asv2 = a_src[col0 + 2 * 16 + lr], asv3 = a_src[col0 + 3 * 16 + lr];
    float adv0 = a_dst[col0 + 0 * 16 + lr], adv1 = a_dst[col0 + 1 * 16 + lr];
    float adv2 = a_dst[col0 + 2 * 16 + lr], adv3 = a_dst[col0 + 3 * 16 + lr];
    #pragma unroll
    for (int i = 0; i < 2; i++) {
        #pragma unroll
        for (int q = 0; q < 4; q++) {
            float ps = acc[i][0][q] * asv0 + acc[i][1][q] * asv1 + acc[i][2][q] * asv2 + acc[i][3][q] * asv3;
            float pd = acc[i][0][q] * adv0 + acc[i][1][q] * adv1 + acc[i][2][q] * adv2 + acc[i][3][q] * adv3;
            #pragma unroll
            for (int off = 1; off < 16; off <<= 1) {
                ps += __shfl_xor(ps, off);
                pd += __shfl_xor(pd, off);
            }
            int r = row0 + wave * 32 + i * 16 + lk * 4 + q;
            if (lr == 0 && r < M) {
                asb[r * HEADS + head] = ps;
                adb[r * HEADS + head] = pd;
            }
        }
    }
}

// ---------------- GAT aggregation v2 ----------------
// No max-shift (e = lrelu(as+ad) is O(1) here: exp safe; softmax identical up to rounding).
// Pass A: sum of exp per head, stashing exp(e) per edge in LDS (deg<=128; fallback recompute).
// Pass B: weighted gather, alpha = stash * 1/sum.

__device__ __forceinline__ float lrelu(float x) { return x > 0.f ? x : NEG_SLOPE * x; }

// MODE 0: write out [N,HC] fp32 (+bias)
// MODE 1: head-mean + b3 -> write xs2 [N,HID]
template<int MODE>
__global__ __launch_bounds__(256) void gat_aggregate(
        const bf16s* __restrict__ hfeat,
        const float* __restrict__ asb, const float* __restrict__ adb,
        const int* __restrict__ rowptr, const int* __restrict__ esrc,
        const float* __restrict__ bias,
        float* __restrict__ out) {
    __shared__ float4 exps[4][128];   // 8 KB: per-wave exp(e) stash
    int wid = threadIdx.x >> 6, lane = threadIdx.x & 63;
    int d = blockIdx.x * 4 + wid;     // grid exact: 4 waves/block
    int start = rowptr[d], end = rowptr[d + 1];
    int deg = end - start;

    float adv0 = adb[d * HEADS + 0], adv1 = adb[d * HEADS + 1];
    float adv2 = adb[d * HEADS + 2], adv3 = adb[d * HEADS + 3];

    // ---- pass A: per-head sum of exp(e); stash exp(e) in LDS ----
    float s0 = 0.f, s1 = 0.f, s2 = 0.f, s3 = 0.f;
    for (int j = start + lane; j < end; j += 64) {
        int s = esrc[j];
        const float4 av = *reinterpret_cast<const float4*>(asb + (size_t)s * HEADS);
        float e0 = __expf(lrelu(av.x + adv0));
        float e1 = __expf(lrelu(av.y + adv1));
        float e2 = __expf(lrelu(av.z + adv2));
        float e3 = __expf(lrelu(av.w + adv3));
        int idx = j - start;
        if (idx < 128) {
            float4 ev; ev.x = e0; ev.y = e1; ev.z = e2; ev.w = e3;
            exps[wid][idx] = ev;
        }
        s0 += e0; s1 += e1; s2 += e2; s3 += e3;
    }
    #pragma unroll
    for (int off = 32; off > 0; off >>= 1) {
        s0 += __shfl_xor(s0, off);
        s1 += __shfl_xor(s1, off);
        s2 += __shfl_xor(s2, off);
        s3 += __shfl_xor(s3, off);
    }
    float r0 = 1.f / (s0 + 1e-16f), r1 = 1.f / (s1 + 1e-16f);
    float r2 = 1.f / (s2 + 1e-16f), r3 = 1.f / (s3 + 1e-16f);

    // ---- pass B: weighted gather; 2 edges/iter (half-wave each); lane owns 8 cols ----
    int half = lane >> 5;
    int cl = lane & 31;
    int hsel = cl >> 3;
    float rdh = (hsel == 0) ? r0 : (hsel == 1) ? r1 : (hsel == 2) ? r2 : r3;
    float adh = (hsel == 0) ? adv0 : (hsel == 1) ? adv1 : (hsel == 2) ? adv2 : adv3;

    float av0 = 0.f, av1 = 0.f, av2 = 0.f, av3 = 0.f;
    float av4 = 0.f, av5 = 0.f, av6 = 0.f, av7 = 0.f;
    int nfull = deg & ~1;
    for (int j = 0; j < nfull; j += 2) {
        int idx = j + half;
        int s = esrc[start + idx];
        float al;
        if (idx < 128) {
            al = reinterpret_cast<const float*>(&exps[wid][idx])[hsel] * rdh;
        } else {
            al = __expf(lrelu(asb[(size_t)s * HEADS + hsel] + adh)) * rdh;
        }
        const bf16x8 v = *reinterpret_cast<const bf16x8*>(hfeat + (size_t)s * HC + cl * 8);
        av0 += al * bs2f(v[0]); av1 += al * bs2f(v[1]);
        av2 += al * bs2f(v[2]); av3 += al * bs2f(v[3]);
        av4 += al * bs2f(v[4]); av5 += al * bs2f(v[5]);
        av6 += al * bs2f(v[6]); av7 += al * bs2f(v[7]);
    }
    if ((deg & 1) && half == 0) {   // odd tail: half 0 only
        int idx = nfull;
        int s = esrc[start + idx];
        float al;
        if (idx < 128) {
            al = reinterpret_cast<const float*>(&exps[wid][idx])[hsel] * rdh;
        } else {
            al = __expf(lrelu(asb[(size_t)s * HEADS + hsel] + adh)) * rdh;
        }
        const bf16x8 v = *reinterpret_cast<const bf16x8*>(hfeat + (size_t)s * HC + cl * 8);
        av0 += al * bs2f(v[0]); av1 += al * bs2f(v[1]);
        av2 += al * bs2f(v[2]); av3 += al * bs2f(v[3]);
        av4 += al * bs2f(v[4]); av5 += al * bs2f(v[5]);
        av6 += al * bs2f(v[6]); av7 += al * bs2f(v[7]);
    }
    av0 += __shfl_xor(av0, 32); av1 += __shfl_xor(av1, 32);
    av2 += __shfl_xor(av2, 32); av3 += __shfl_xor(av3, 32);
    av4 += __shfl_xor(av4, 32); av5 += __shfl_xor(av5, 32);
    av6 += __shfl_xor(av6, 32); av7 += __shfl_xor(av7, 32);

    if constexpr (MODE == 0) {
        if (half == 0) {
            const float4 b0 = *reinterpret_cast<const float4*>(bias + cl * 8);
            const float4 b1 = *reinterpret_cast<const float4*>(bias + cl * 8 + 4);
            av0 += b0.x; av1 += b0.y; av2 += b0.z; av3 += b0.w;
            av4 += b1.x; av5 += b1.y; av6 += b1.z; av7 += b1.w;
            float4 o0; o0.x = av0; o0.y = av1; o0.z = av2; o0.w = av3;
            float4 o1; o1.x = av4; o1.y = av5; o1.z = av6; o1.w = av7;
            *reinterpret_cast<float4*>(out + (size_t)d * HC + cl * 8) = o0;
            *reinterpret_cast<float4*>(out + (size_t)d * HC + cl * 8 + 4) = o1;
        }
    } else {
        float h0 = av0 + __shfl_xor(av0, 8); h0 += __shfl_xor(h0, 16);
        float h1 = av1 + __shfl_xor(av1, 8); h1 += __shfl_xor(h1, 16);
        float h2 = av2 + __shfl_xor(av2, 8); h2 += __shfl_xor(h2, 16);
        float h3 = av3 + __shfl_xor(av3, 8); h3 += __shfl_xor(h3, 16);
        float h4 = av4 + __shfl_xor(av4, 8); h4 += __shfl_xor(h4, 16);
        float h5 = av5 + __shfl_xor(av5, 8); h5 += __shfl_xor(h5, 16);
        float h6 = av6 + __shfl_xor(av6, 8); h6 += __shfl_xor(h6, 16);
        float h7 = av7 + __shfl_xor(av7, 8); h7 += __shfl_xor(h7, 16);
        if (half == 0 && cl < 8) {
            int c = cl * 8;
            float4 o0, o1;
            o0.x = 0.25f * h0 + bias[c + 0]; o0.y = 0.25f * h1 + bias[c + 1];
            o0.z = 0.25f * h2 + bias[c + 2]; o0.w = 0.25f * h3 + bias[c + 3];
            o1.x = 0.25f * h4 + bias[c + 4]; o1.y = 0.25f * h5 + bias[c + 5];
            o1.z = 0.25f * h6 + bias[c + 6]; o1.w = 0.25f * h7 + bias[c + 7];
            *reinterpret_cast<float4*>(out + (size_t)d * HID + c) = o0;
            *reinterpret_cast<float4*>(out + (size_t)d * HID + c + 4) = o1;
        }
    }
}

// ---------------- BatchNorm ----------------

__global__ void bn_stats(const float* __restrict__ x, float* colsum, float* colsq, int n) {
    int col = threadIdx.x;  // 256 threads
    float s = 0.f, q = 0.f;
    for (int r = blockIdx.x; r < n; r += gridDim.x) {
        float v = x[(size_t)r * HC + col];
        s += v;
        q += v * v;
    }
    atomicAdd(&colsum[col], s);
    atomicAdd(&colsq[col], q);
}

// computes scale/shift, then zeroes colstats for the next user
__global__ void bn_finalize(float* colsum, float* colsq,
                            const float* __restrict__ g, const float* __restrict__ be,
                            float* scale, float* shift, int n) {
    int col = threadIdx.x;  // 256
    float mu = colsum[col] / (float)n;
    float var = colsq[col] / (float)n - mu * mu;
    float sc = g[col] * rsqrtf(var + BN_EPS);
    scale[col] = sc;
    shift[col] = be[col] - mu * sc;
    colsum[col] = 0.f;
    colsq[col] = 0.f;
}

__global__ void bn_apply_elu(const float* __restrict__ x,
                             const float* __restrict__ scale, const float* __restrict__ shift,
                             float* __restrict__ xs_out, bf16s* __restrict__ act, int n) {
    int col = threadIdx.x;  // 256
    float sc = scale[col], sh = shift[col];
    for (int r = blockIdx.x; r < n; r += gridDim.x) {
        float v = x[(size_t)r * HC + col];
        float y = v * sc + sh;
        xs_out[(size_t)r * HC + col] = y;
        float e = y > 0.f ? y : __expf(y) - 1.f;
        act[(size_t)r * HC + col] = f2bs(e);
    }
}

// ---------------- pool + final linear: one block per graph ----------------

__global__ __launch_bounds__(256) void pool_final(
        const float* __restrict__ xs2, const int* __restrict__ batch,
        const float* __restrict__ Wlin, const float* __restrict__ blin,
        float* __restrict__ pooled_out, float* __restrict__ out_final) {
    __shared__ float red[4][HID];
    int g = blockIdx.x;
    int tid = threadIdx.x;
    int w = tid >> 6, lane = tid & 63;

    // bounds via binary search on sorted batch (all threads redundantly)
    int lo = 0, hi = N_NODES;
    while (lo < hi) { int mid = (lo + hi) >> 1; if (batch[mid] < g) lo = mid + 1; else hi = mid; }
    int a = lo;
    lo = 0; hi = N_NODES;
    while (lo < hi) { int mid = (lo + hi) >> 1; if (batch[mid] < g + 1) lo = mid + 1; else hi = mid; }
    int b = lo;

    // each wave covers rows a+w, a+w+4, ... ; lane = column
    float acc = 0.f;
    for (int n = a + w; n < b; n += 4) acc += xs2[(size_t)n * HID + lane];
    red[w][lane] = acc;
    __syncthreads();

    if (w == 0) {
        float pooled = (red[0][lane] + red[1][lane] + red[2][lane] + red[3][lane])
                       / fmaxf((float)(b - a), 1.f);
        pooled_out[g * HID + lane] = pooled;
        #pragma unroll
        for (int o = 0; o < OUT_DIM; o++) {
            float p = pooled * Wlin[lane * OUT_DIM + o];
            #pragma unroll
            for (int off = 32; off > 0; off >>= 1) p += __shfl_xor(p, off);
            if (lane == 0) out_final[g * OUT_DIM + o] = p + blin[o];
        }
    }
}

// ---------------- host side ----------------

extern "C" void kernel_launch(void* const* d_in, const int* in_sizes, int n_in,
                              void* d_out, int out_size, void* d_ws, size_t ws_size,
                              hipStream_t stream) {
    const float* x     = (const float*)d_in[0];
    const int*   ei    = (const int*)d_in[1];   // [2,E]
    const int*   batch = (const int*)d_in[2];
    const float* W1  = (const float*)d_in[3];
    const float* as1 = (const float*)d_in[4];
    const float* ad1 = (const float*)d_in[5];
    const float* b1  = (const float*)d_in[6];
    const float* g1  = (const float*)d_in[7];
    const float* be1 = (const float*)d_in[8];
    const float* W2  = (const float*)d_in[9];
    const float* as2 = (const float*)d_in[10];
    const float* ad2 = (const float*)d_in[11];
    const float* b2  = (const float*)d_in[12];
    const float* g2  = (const float*)d_in[13];
    const float* be2 = (const float*)d_in[14];
    const float* W3  = (const float*)d_in[15];
    const float* as3 = (const float*)d_in[16];
    const float* ad3 = (const float*)d_in[17];
    const float* b3  = (const float*)d_in[18];
    const float* Wlin = (const float*)d_in[19];
    const float* blin = (const float*)d_in[20];

    // output regions
    float* out_final = (float*)d_out;                 // [128,10]
    float* xs0 = out_final + NUM_GRAPHS * OUT_DIM;    // [N,256]
    float* xs1 = xs0 + (size_t)N_NODES * HC;          // [N,256]
    float* xs2 = xs1 + (size_t)N_NODES * HC;          // [N,64]
    float* pooled_out = xs2 + (size_t)N_NODES * HID;  // [128,64]

    // workspace carve
    char* p = (char*)d_ws;
    auto alloc = [&](size_t bytes) { char* r = p; p += (bytes + 255) & ~(size_t)255; return (void*)r; };
    bf16s* hfeat  = (bf16s*)alloc((size_t)N_NODES * HC * 2);
    bf16s* actC   = (bf16s*)alloc((size_t)N_NODES * HC * 2);
    bf16s* xb     = (bf16s*)alloc((size_t)N_NODES * F_IN * 2);
    float* gatB   = (float*)alloc((size_t)N_NODES * HC * 4);
    bf16s* Wt1    = (bf16s*)alloc((size_t)HC * F_IN * 2);
    bf16s* Wt2    = (bf16s*)alloc((size_t)HC * HC * 2);
    bf16s* Wt3    = (bf16s*)alloc((size_t)HC * HC * 2);
    float* asb    = (float*)alloc((size_t)N_NODES * HEADS * 4);
    float* adb    = (float*)alloc((size_t)N_NODES * HEADS * 4);
    int*   deg    = (int*)alloc((size_t)N_NODES * 4);
    int*   cursor = (int*)alloc((size_t)N_NODES * 4);
    int*   rowptr = (int*)alloc((size_t)(N_NODES + 1) * 4);
    int*   esrc   = (int*)alloc((size_t)(N_EDGES + N_NODES) * 4);
    float* colstats = (float*)alloc(2 * HC * 4);
    float* colsum = colstats;
    float* colsq  = colstats + HC;
    float* scale  = (float*)alloc(HC * 4);
    float* shift  = (float*)alloc(HC * 4);

    const int ETOT = N_EDGES + N_NODES;

    // ---- CSR build (once, reused for all 3 layers) ----
    fill_i32<<<(N_NODES + 255) / 256, 256, 0, stream>>>(deg, N_NODES, 1);  // self-loop
    count_deg<<<(N_EDGES + 255) / 256, 256, 0, stream>>>(ei + N_EDGES, deg, N_EDGES);
    scan_deg<<<1, 1024, 0, stream>>>(deg, rowptr, cursor, N_NODES);
    fill_csr<<<(ETOT + 255) / 256, 256, 0, stream>>>(ei, cursor, esrc, N_EDGES, N_NODES);

    // ---- input/weight prep ----
    conv_bf16<<<((N_NODES * F_IN / 4) + 255) / 256, 256, 0, stream>>>(x, xb, N_NODES * F_IN / 4);
    prep_weights<<<(HC * F_IN + 2 * HC * HC + 255) / 256, 256, 0, stream>>>(W1, W2, W3, Wt1, Wt2, Wt3);
    fill_f32<<<2, 256, 0, stream>>>(colstats, 2 * HC, 0.f);

    int agg_blocks = N_NODES / 4;   // exactly 4 waves/block
    dim3 ggrid((N_NODES + 127) / 128, HEADS);

    // ---- layer 1 ----
    {
        gemm_bf16<<<ggrid, 256, 0, stream>>>(xb, Wt1, hfeat, as1, ad1, asb, adb, N_NODES, F_IN);
        gat_aggregate<0><<<agg_blocks, 256, 0, stream>>>(hfeat, asb, adb, rowptr, esrc, b1, gatB);
        bn_stats<<<512, 256, 0, stream>>>(gatB, colsum, colsq, N_NODES);
        bn_finalize<<<1, 256, 0, stream>>>(colsum, colsq, g1, be1, scale, shift, N_NODES);
        bn_apply_elu<<<2048, 256, 0, stream>>>(gatB, scale, shift, xs0, actC, N_NODES);
    }
    // ---- layer 2 ----
    {
        gemm_bf16<<<ggrid, 256, 0, stream>>>(actC, Wt2, hfeat, as2, ad2, asb, adb, N_NODES, HC);
        gat_aggregate<0><<<agg_blocks, 256, 0, stream>>>(hfeat, asb, adb, rowptr, esrc, b2, gatB);
        bn_stats<<<512, 256, 0, stream>>>(gatB, colsum, colsq, N_NODES);
        bn_finalize<<<1, 256, 0, stream>>>(colsum, colsq, g2, be2, scale, shift, N_NODES);
        bn_apply_elu<<<2048, 256, 0, stream>>>(gatB, scale, shift, xs1, actC, N_NODES);
    }
    // ---- layer 3 ----
    {
        gemm_bf16<<<ggrid, 256, 0, stream>>>(actC, Wt3, hfeat, as3, ad3, asb, adb, N_NODES, HC);
        gat_aggregate<1><<<agg_blocks, 256, 0, stream>>>(hfeat, asb, adb, rowptr, esrc, b3, xs2);
    }
    // ---- pool + final linear ----
    pool_final<<<NUM_GRAPHS, 256, 0, stream>>>(xs2, batch, Wlin, blin, pooled_out, out_final);
}

// Round 7
// 350.914 us; speedup vs baseline: 1.7519x; 1.0958x over previous
//
#include <hip/hip_runtime.h>
#include <hip/hip_bf16.h>
#include <math.h>

#define N_NODES 20000
#define N_EDGES 640000
#define F_IN 128
#define HID 64
#define HEADS 4
#define HC 256      // HEADS*HID
#define OUT_DIM 10
#define NUM_GRAPHS 128
#define NEG_SLOPE 0.2f
#define BN_EPS 1e-5f

typedef short bf16s;
using bf16x8 = __attribute__((ext_vector_type(8))) short;
using bf16x4 = __attribute__((ext_vector_type(4))) short;
using f32x4 = __attribute__((ext_vector_type(4))) float;

__device__ __forceinline__ float bs2f(short s) {
    unsigned int u = ((unsigned int)(unsigned short)s) << 16;
    return __builtin_bit_cast(float, u);
}
__device__ __forceinline__ short f2bs(float f) {
    unsigned int u = __builtin_bit_cast(unsigned int, f);
    unsigned int r = u + 0x7FFFu + ((u >> 16) & 1u);
    return (short)(r >> 16);
}

// ---------------- utility kernels ----------------

__global__ void fill_i32(int* p, int n, int val) {
    int tid = blockIdx.x * blockDim.x + threadIdx.x;
    if (tid < n) p[tid] = val;
}

__global__ void fill_f32(float* p, int n, float val) {
    int tid = blockIdx.x * blockDim.x + threadIdx.x;
    if (tid < n) p[tid] = val;
}

__global__ void conv_bf16(const float* __restrict__ in, bf16s* __restrict__ out, int n4) {
    int tid = blockIdx.x * blockDim.x + threadIdx.x;
    if (tid >= n4) return;
    float4 v = reinterpret_cast<const float4*>(in)[tid];
    bf16x4 o;
    o[0] = f2bs(v.x); o[1] = f2bs(v.y); o[2] = f2bs(v.z); o[3] = f2bs(v.w);
    reinterpret_cast<bf16x4*>(out)[tid] = o;
}

// all three W transposes in one kernel: W [K][256] fp32 -> Wt [256][K] bf16
__global__ void prep_weights(const float* __restrict__ W1, const float* __restrict__ W2,
                             const float* __restrict__ W3,
                             bf16s* __restrict__ Wt1, bf16s* __restrict__ Wt2,
                             bf16s* __restrict__ Wt3) {
    int tid = blockIdx.x * blockDim.x + threadIdx.x;
    if (tid < HC * F_IN) {
        int c = tid >> 7, k = tid & (F_IN - 1);
        Wt1[tid] = f2bs(W1[(size_t)k * HC + c]);
    } else if (tid < HC * F_IN + HC * HC) {
        int t = tid - HC * F_IN;
        int c = t >> 8, k = t & (HC - 1);
        Wt2[t] = f2bs(W2[(size_t)k * HC + c]);
    } else if (tid < HC * F_IN + 2 * HC * HC) {
        int t = tid - HC * F_IN - HC * HC;
        int c = t >> 8, k = t & (HC - 1);
        Wt3[t] = f2bs(W3[(size_t)k * HC + c]);
    }
}

// ---------------- CSR build ----------------

__global__ void count_deg(const int* __restrict__ ei_dst, int* deg, int E) {
    int tid = blockIdx.x * blockDim.x + threadIdx.x;
    if (tid < E) atomicAdd(&deg[ei_dst[tid]], 1);
}

// single-block scan, shfl-based: rowptr[i+1] = incl_prefix(deg)[i]; cursor[i] = excl prefix
__global__ void scan_deg(const int* __restrict__ deg, int* __restrict__ rowptr,
                         int* __restrict__ cursor, int n) {
    __shared__ int wsum[16];
    __shared__ int carry_s;
    int tid = threadIdx.x;          // 1024 threads
    int wid = tid >> 6, lane = tid & 63;
    if (tid == 0) { carry_s = 0; rowptr[0] = 0; }
    __syncthreads();
    for (int base = 0; base < n; base += 1024) {
        int i = base + tid;
        int v = (i < n) ? deg[i] : 0;
        int x = v;
        #pragma unroll
        for (int off = 1; off < 64; off <<= 1) {
            int t = __shfl_up(x, off);
            if (lane >= off) x += t;
        }
        if (lane == 63) wsum[wid] = x;
        __syncthreads();
        if (tid == 0) {
            int acc = carry_s;
            #pragma unroll
            for (int w = 0; w < 16; w++) { int t = wsum[w]; wsum[w] = acc; acc += t; }
            carry_s = acc;
        }
        __syncthreads();
        int inc = x + wsum[wid];
        if (i < n) { rowptr[i + 1] = inc; cursor[i] = inc - v; }
        __syncthreads();
    }
}

__global__ void fill_csr(const int* __restrict__ ei, int* cursor, int* esrc, int E, int n) {
    int tid = blockIdx.x * blockDim.x + threadIdx.x;
    if (tid < E) {
        int src = ei[tid];
        int dst = ei[E + tid];
        int pos = atomicAdd(&cursor[dst], 1);
        esrc[pos] = src;
    } else if (tid < E + n) {
        int node = tid - E;
        int pos = atomicAdd(&cursor[node], 1);
        esrc[pos] = node;
    }
}

// ---------------- bf16 MFMA GEMM + fused attention coefficients ----------------
// H[M,256] = A[M,K] @ Wt^T; blockIdx.y == head; epilogue computes asb/adb.

__global__ __launch_bounds__(256) void gemm_bf16(
        const bf16s* __restrict__ A, const bf16s* __restrict__ Wt,
        bf16s* __restrict__ Hout,
        const float* __restrict__ a_src, const float* __restrict__ a_dst,
        float* __restrict__ asb, float* __restrict__ adb,
        int M, int K) {
    __shared__ bf16s As[128][72];
    __shared__ bf16s Bs[64][72];
    int tid = threadIdx.x;
    int wave = tid >> 6, lane = tid & 63;
    int row0 = blockIdx.x * 128;
    int head = blockIdx.y;
    int col0 = head * 64;
    int lr = lane & 15, lk = lane >> 4;

    f32x4 acc[2][4];
    #pragma unroll
    for (int i = 0; i < 2; i++)
        #pragma unroll
        for (int j = 0; j < 4; j++)
            acc[i][j] = (f32x4){0.f, 0.f, 0.f, 0.f};

    for (int k0 = 0; k0 < K; k0 += 64) {
        #pragma unroll
        for (int i = 0; i < 4; i++) {
            int idx = tid + i * 256;
            int r = idx >> 3, ch = idx & 7;
            int gr = row0 + r;
            bf16x8 v = {};
            if (gr < M) v = *reinterpret_cast<const bf16x8*>(A + (size_t)gr * K + k0 + ch * 8);
            *reinterpret_cast<bf16x8*>(&As[r][ch * 8]) = v;
        }
        #pragma unroll
        for (int i = 0; i < 2; i++) {
            int idx = tid + i * 256;
            int r = idx >> 3, ch = idx & 7;
            bf16x8 v = *reinterpret_cast<const bf16x8*>(Wt + (size_t)(col0 + r) * K + k0 + ch * 8);
            *reinterpret_cast<bf16x8*>(&Bs[r][ch * 8]) = v;
        }
        __syncthreads();
        #pragma unroll
        for (int ks = 0; ks < 2; ks++) {
            bf16x8 bfr[4];
            #pragma unroll
            for (int j = 0; j < 4; j++)
                bfr[j] = *reinterpret_cast<const bf16x8*>(&Bs[j * 16 + lr][ks * 32 + lk * 8]);
            #pragma unroll
            for (int i = 0; i < 2; i++) {
                bf16x8 afr = *reinterpret_cast<const bf16x8*>(&As[wave * 32 + i * 16 + lr][ks * 32 + lk * 8]);
                #pragma unroll
                for (int j = 0; j < 4; j++)
                    acc[i][j] = __builtin_amdgcn_mfma_f32_16x16x32_bf16(afr, bfr[j], acc[i][j], 0, 0, 0);
            }
        }
        __syncthreads();
    }

    // store H (C/D layout: col = lane&15, row = (lane>>4)*4 + q)
    #pragma unroll
    for (int i = 0; i < 2; i++) {
        #pragma unroll
        for (int q = 0; q < 4; q++) {
            int r = row0 + wave * 32 + i * 16 + lk * 4 + q;
            if (r < M) {
                #pragma unroll
                for (int j = 0; j < 4; j++) {
                    int c = col0 + j * 16 + lr;
                    Hout[(size_t)r * HC + c] = f2bs(acc[i][j][q]);
                }
            }
        }
    }

    // fused attn coefficients: per-row dot with a_src/a_dst for this head
    float asv0 = a_src[col0 + 0 * 16 + lr], asv1 = a_src[col0 + 1 * 16 + lr];
    float asv2 = a_src[col0 + 2 * 16 + lr], asv3 = a_src[col0 + 3 * 16 + lr];
    float adv0 = a_dst[col0 + 0 * 16 + lr], adv1 = a_dst[col0 + 1 * 16 + lr];
    float adv2 = a_dst[col0 + 2 * 16 + lr], adv3 = a_dst[col0 + 3 * 16 + lr];
    #pragma unroll
    for (int i = 0; i < 2; i++) {
        #pragma unroll
        for (int q = 0; q < 4; q++) {
            float ps = acc[i][0][q] * asv0 + acc[i][1][q] * asv1 + acc[i][2][q] * asv2 + acc[i][3][q] * asv3;
            float pd = acc[i][0][q] * adv0 + acc[i][1][q] * adv1 + acc[i][2][q] * adv2 + acc[i][3][q] * adv3;
            #pragma unroll
            for (int off = 1; off < 16; off <<= 1) {
                ps += __shfl_xor(ps, off);
                pd += __shfl_xor(pd, off);
            }
            int r = row0 + wave * 32 + i * 16 + lk * 4 + q;
            if (lr == 0 && r < M) {
                asb[r * HEADS + head] = ps;
                adb[r * HEADS + head] = pd;
            }
        }
    }
}

// ---------------- GAT aggregation v3 ----------------
// Pass A: per-head sum of exp(e); stash exp(e) AND src index per edge in LDS (deg<=128).
// Pass B: weighted gather, 4 edges in flight per wave (2 per half, unrolled x2);
//         edge index + alpha come from LDS -> only the h-row gather touches global.

__device__ __forceinline__ float lrelu(float x) { return x > 0.f ? x : NEG_SLOPE * x; }

// MODE 0: write out [N,HC] fp32 (+bias)
// MODE 1: head-mean + b3 -> write xs2 [N,HID]
template<int MODE>
__global__ __launch_bounds__(256) void gat_aggregate(
        const bf16s* __restrict__ hfeat,
        const float* __restrict__ asb, const float* __restrict__ adb,
        const int* __restrict__ rowptr, const int* __restrict__ esrc,
        const float* __restrict__ bias,
        float* __restrict__ out) {
    __shared__ float4 exps[4][128];   // 8 KB: per-wave exp(e) stash
    __shared__ int    srcs[4][128];   // 2 KB: per-wave src index stash
    int wid = threadIdx.x >> 6, lane = threadIdx.x & 63;
    int d = blockIdx.x * 4 + wid;     // grid exact: 4 waves/block
    int start = rowptr[d], end = rowptr[d + 1];
    int deg = end - start;

    float adv0 = adb[d * HEADS + 0], adv1 = adb[d * HEADS + 1];
    float adv2 = adb[d * HEADS + 2], adv3 = adb[d * HEADS + 3];

    // ---- pass A: per-head sum of exp(e); stash exp + src in LDS ----
    float s0 = 0.f, s1 = 0.f, s2 = 0.f, s3 = 0.f;
    for (int j = start + lane; j < end; j += 64) {
        int s = esrc[j];
        const float4 av = *reinterpret_cast<const float4*>(asb + (size_t)s * HEADS);
        float e0 = __expf(lrelu(av.x + adv0));
        float e1 = __expf(lrelu(av.y + adv1));
        float e2 = __expf(lrelu(av.z + adv2));
        float e3 = __expf(lrelu(av.w + adv3));
        int idx = j - start;
        if (idx < 128) {
            float4 ev; ev.x = e0; ev.y = e1; ev.z = e2; ev.w = e3;
            exps[wid][idx] = ev;
            srcs[wid][idx] = s;
        }
        s0 += e0; s1 += e1; s2 += e2; s3 += e3;
    }
    #pragma unroll
    for (int off = 32; off > 0; off >>= 1) {
        s0 += __shfl_xor(s0, off);
        s1 += __shfl_xor(s1, off);
        s2 += __shfl_xor(s2, off);
        s3 += __shfl_xor(s3, off);
    }
    float r0 = 1.f / (s0 + 1e-16f), r1 = 1.f / (s1 + 1e-16f);
    float r2 = 1.f / (s2 + 1e-16f), r3 = 1.f / (s3 + 1e-16f);

    // ---- pass B ----
    int half = lane >> 5;
    int cl = lane & 31;
    int hsel = cl >> 3;
    float rdh = (hsel == 0) ? r0 : (hsel == 1) ? r1 : (hsel == 2) ? r2 : r3;
    float adh = (hsel == 0) ? adv0 : (hsel == 1) ? adv1 : (hsel == 2) ? adv2 : adv3;

    float a0 = 0.f, a1 = 0.f, a2 = 0.f, a3 = 0.f, a4 = 0.f, a5 = 0.f, a6 = 0.f, a7 = 0.f;
    float b0 = 0.f, b1 = 0.f, b2 = 0.f, b3 = 0.f, b4 = 0.f, b5 = 0.f, b6 = 0.f, b7 = 0.f;

    int nfull = deg & ~3;
    for (int j = 0; j < nfull; j += 4) {
        int iA = j + half;
        int iB = j + 2 + half;
        int sA, sB;
        float alA, alB;
        if (iB < 128) {   // common case: both from LDS stash
            sA = srcs[wid][iA];
            sB = srcs[wid][iB];
            alA = reinterpret_cast<const float*>(&exps[wid][iA])[hsel] * rdh;
            alB = reinterpret_cast<const float*>(&exps[wid][iB])[hsel] * rdh;
        } else {
            sA = (iA < 128) ? srcs[wid][iA] : esrc[start + iA];
            sB = esrc[start + iB];
            alA = (iA < 128) ? reinterpret_cast<const float*>(&exps[wid][iA])[hsel] * rdh
                             : __expf(lrelu(asb[(size_t)sA * HEADS + hsel] + adh)) * rdh;
            alB = __expf(lrelu(asb[(size_t)sB * HEADS + hsel] + adh)) * rdh;
        }
        const bf16x8 vA = *reinterpret_cast<const bf16x8*>(hfeat + (size_t)sA * HC + cl * 8);
        const bf16x8 vB = *reinterpret_cast<const bf16x8*>(hfeat + (size_t)sB * HC + cl * 8);
        a0 += alA * bs2f(vA[0]); a1 += alA * bs2f(vA[1]);
        a2 += alA * bs2f(vA[2]); a3 += alA * bs2f(vA[3]);
        a4 += alA * bs2f(vA[4]); a5 += alA * bs2f(vA[5]);
        a6 += alA * bs2f(vA[6]); a7 += alA * bs2f(vA[7]);
        b0 += alB * bs2f(vB[0]); b1 += alB * bs2f(vB[1]);
        b2 += alB * bs2f(vB[2]); b3 += alB * bs2f(vB[3]);
        b4 += alB * bs2f(vB[4]); b5 += alB * bs2f(vB[5]);
        b6 += alB * bs2f(vB[6]); b7 += alB * bs2f(vB[7]);
    }
    // tail (0..3 edges): half 0 takes even offsets, half 1 odd
    for (int j = nfull + half; j < deg; j += 2) {
        int s = (j < 128) ? srcs[wid][j] : esrc[start + j];
        float al = (j < 128) ? reinterpret_cast<const float*>(&exps[wid][j])[hsel] * rdh
                             : __expf(lrelu(asb[(size_t)s * HEADS + hsel] + adh)) * rdh;
        const bf16x8 v = *reinterpret_cast<const bf16x8*>(hfeat + (size_t)s * HC + cl * 8);
        a0 += al * bs2f(v[0]); a1 += al * bs2f(v[1]);
        a2 += al * bs2f(v[2]); a3 += al * bs2f(v[3]);
        a4 += al * bs2f(v[4]); a5 += al * bs2f(v[5]);
        a6 += al * bs2f(v[6]); a7 += al * bs2f(v[7]);
    }
    float av0 = a0 + b0, av1 = a1 + b1, av2 = a2 + b2, av3 = a3 + b3;
    float av4 = a4 + b4, av5 = a5 + b5, av6 = a6 + b6, av7 = a7 + b7;

    av0 += __shfl_xor(av0, 32); av1 += __shfl_xor(av1, 32);
    av2 += __shfl_xor(av2, 32); av3 += __shfl_xor(av3, 32);
    av4 += __shfl_xor(av4, 32); av5 += __shfl_xor(av5, 32);
    av6 += __shfl_xor(av6, 32); av7 += __shfl_xor(av7, 32);

    if constexpr (MODE == 0) {
        if (half == 0) {
            const float4 bb0 = *reinterpret_cast<const float4*>(bias + cl * 8);
            const float4 bb1 = *reinterpret_cast<const float4*>(bias + cl * 8 + 4);
            av0 += bb0.x; av1 += bb0.y; av2 += bb0.z; av3 += bb0.w;
            av4 += bb1.x; av5 += bb1.y; av6 += bb1.z; av7 += bb1.w;
            float4 o0; o0.x = av0; o0.y = av1; o0.z = av2; o0.w = av3;
            float4 o1; o1.x = av4; o1.y = av5; o1.z = av6; o1.w = av7;
            *reinterpret_cast<float4*>(out + (size_t)d * HC + cl * 8) = o0;
            *reinterpret_cast<float4*>(out + (size_t)d * HC + cl * 8 + 4) = o1;
        }
    } else {
        float h0 = av0 + __shfl_xor(av0, 8); h0 += __shfl_xor(h0, 16);
        float h1 = av1 + __shfl_xor(av1, 8); h1 += __shfl_xor(h1, 16);
        float h2 = av2 + __shfl_xor(av2, 8); h2 += __shfl_xor(h2, 16);
        float h3 = av3 + __shfl_xor(av3, 8); h3 += __shfl_xor(h3, 16);
        float h4 = av4 + __shfl_xor(av4, 8); h4 += __shfl_xor(h4, 16);
        float h5 = av5 + __shfl_xor(av5, 8); h5 += __shfl_xor(h5, 16);
        float h6 = av6 + __shfl_xor(av6, 8); h6 += __shfl_xor(h6, 16);
        float h7 = av7 + __shfl_xor(av7, 8); h7 += __shfl_xor(h7, 16);
        if (half == 0 && cl < 8) {
            int c = cl * 8;
            float4 o0, o1;
            o0.x = 0.25f * h0 + bias[c + 0]; o0.y = 0.25f * h1 + bias[c + 1];
            o0.z = 0.25f * h2 + bias[c + 2]; o0.w = 0.25f * h3 + bias[c + 3];
            o1.x = 0.25f * h4 + bias[c + 4]; o1.y = 0.25f * h5 + bias[c + 5];
            o1.z = 0.25f * h6 + bias[c + 6]; o1.w = 0.25f * h7 + bias[c + 7];
            *reinterpret_cast<float4*>(out + (size_t)d * HID + c) = o0;
            *reinterpret_cast<float4*>(out + (size_t)d * HID + c + 4) = o1;
        }
    }
}

// ---------------- BatchNorm ----------------

__global__ void bn_stats(const float* __restrict__ x, float* colsum, float* colsq, int n) {
    int col = threadIdx.x;  // 256 threads
    float s = 0.f, q = 0.f;
    for (int r = blockIdx.x; r < n; r += gridDim.x) {
        float v = x[(size_t)r * HC + col];
        s += v;
        q += v * v;
    }
    atomicAdd(&colsum[col], s);
    atomicAdd(&colsq[col], q);
}

// computes scale/shift, then zeroes colstats for the next user
__global__ void bn_finalize(float* colsum, float* colsq,
                            const float* __restrict__ g, const float* __restrict__ be,
                            float* scale, float* shift, int n) {
    int col = threadIdx.x;  // 256
    float mu = colsum[col] / (float)n;
    float var = colsq[col] / (float)n - mu * mu;
    float sc = g[col] * rsqrtf(var + BN_EPS);
    scale[col] = sc;
    shift[col] = be[col] - mu * sc;
    colsum[col] = 0.f;
    colsq[col] = 0.f;
}

__global__ void bn_apply_elu(const float* __restrict__ x,
                             const float* __restrict__ scale, const float* __restrict__ shift,
                             float* __restrict__ xs_out, bf16s* __restrict__ act, int n) {
    int col = threadIdx.x;  // 256
    float sc = scale[col], sh = shift[col];
    for (int r = blockIdx.x; r < n; r += gridDim.x) {
        float v = x[(size_t)r * HC + col];
        float y = v * sc + sh;
        xs_out[(size_t)r * HC + col] = y;
        float e = y > 0.f ? y : __expf(y) - 1.f;
        act[(size_t)r * HC + col] = f2bs(e);
    }
}

// ---------------- pool + final linear: one block per graph ----------------

__global__ __launch_bounds__(256) void pool_final(
        const float* __restrict__ xs2, const int* __restrict__ batch,
        const float* __restrict__ Wlin, const float* __restrict__ blin,
        float* __restrict__ pooled_out, float* __restrict__ out_final) {
    __shared__ float red[4][HID];
    int g = blockIdx.x;
    int tid = threadIdx.x;
    int w = tid >> 6, lane = tid & 63;

    // bounds via binary search on sorted batch (all threads redundantly)
    int lo = 0, hi = N_NODES;
    while (lo < hi) { int mid = (lo + hi) >> 1; if (batch[mid] < g) lo = mid + 1; else hi = mid; }
    int a = lo;
    lo = 0; hi = N_NODES;
    while (lo < hi) { int mid = (lo + hi) >> 1; if (batch[mid] < g + 1) lo = mid + 1; else hi = mid; }
    int b = lo;

    // each wave covers rows a+w, a+w+4, ... ; lane = column
    float acc = 0.f;
    for (int n = a + w; n < b; n += 4) acc += xs2[(size_t)n * HID + lane];
    red[w][lane] = acc;
    __syncthreads();

    if (w == 0) {
        float pooled = (red[0][lane] + red[1][lane] + red[2][lane] + red[3][lane])
                       / fmaxf((float)(b - a), 1.f);
        pooled_out[g * HID + lane] = pooled;
        #pragma unroll
        for (int o = 0; o < OUT_DIM; o++) {
            float p = pooled * Wlin[lane * OUT_DIM + o];
            #pragma unroll
            for (int off = 32; off > 0; off >>= 1) p += __shfl_xor(p, off);
            if (lane == 0) out_final[g * OUT_DIM + o] = p + blin[o];
        }
    }
}

// ---------------- host side ----------------

extern "C" void kernel_launch(void* const* d_in, const int* in_sizes, int n_in,
                              void* d_out, int out_size, void* d_ws, size_t ws_size,
                              hipStream_t stream) {
    const float* x     = (const float*)d_in[0];
    const int*   ei    = (const int*)d_in[1];   // [2,E]
    const int*   batch = (const int*)d_in[2];
    const float* W1  = (const float*)d_in[3];
    const float* as1 = (const float*)d_in[4];
    const float* ad1 = (const float*)d_in[5];
    const float* b1  = (const float*)d_in[6];
    const float* g1  = (const float*)d_in[7];
    const float* be1 = (const float*)d_in[8];
    const float* W2  = (const float*)d_in[9];
    const float* as2 = (const float*)d_in[10];
    const float* ad2 = (const float*)d_in[11];
    const float* b2  = (const float*)d_in[12];
    const float* g2  = (const float*)d_in[13];
    const float* be2 = (const float*)d_in[14];
    const float* W3  = (const float*)d_in[15];
    const float* as3 = (const float*)d_in[16];
    const float* ad3 = (const float*)d_in[17];
    const float* b3  = (const float*)d_in[18];
    const float* Wlin = (const float*)d_in[19];
    const float* blin = (const float*)d_in[20];

    // output regions
    float* out_final = (float*)d_out;                 // [128,10]
    float* xs0 = out_final + NUM_GRAPHS * OUT_DIM;    // [N,256]
    float* xs1 = xs0 + (size_t)N_NODES * HC;          // [N,256]
    float* xs2 = xs1 + (size_t)N_NODES * HC;          // [N,64]
    float* pooled_out = xs2 + (size_t)N_NODES * HID;  // [128,64]

    // workspace carve
    char* p = (char*)d_ws;
    auto alloc = [&](size_t bytes) { char* r = p; p += (bytes + 255) & ~(size_t)255; return (void*)r; };
    bf16s* hfeat  = (bf16s*)alloc((size_t)N_NODES * HC * 2);
    bf16s* actC   = (bf16s*)alloc((size_t)N_NODES * HC * 2);
    bf16s* xb     = (bf16s*)alloc((size_t)N_NODES * F_IN * 2);
    float* gatB   = (float*)alloc((size_t)N_NODES * HC * 4);
    bf16s* Wt1    = (bf16s*)alloc((size_t)HC * F_IN * 2);
    bf16s* Wt2    = (bf16s*)alloc((size_t)HC * HC * 2);
    bf16s* Wt3    = (bf16s*)alloc((size_t)HC * HC * 2);
    float* asb    = (float*)alloc((size_t)N_NODES * HEADS * 4);
    float* adb    = (float*)alloc((size_t)N_NODES * HEADS * 4);
    int*   deg    = (int*)alloc((size_t)N_NODES * 4);
    int*   cursor = (int*)alloc((size_t)N_NODES * 4);
    int*   rowptr = (int*)alloc((size_t)(N_NODES + 1) * 4);
    int*   esrc   = (int*)alloc((size_t)(N_EDGES + N_NODES) * 4);
    float* colstats = (float*)alloc(2 * HC * 4);
    float* colsum = colstats;
    float* colsq  = colstats + HC;
    float* scale  = (float*)alloc(HC * 4);
    float* shift  = (float*)alloc(HC * 4);

    const int ETOT = N_EDGES + N_NODES;

    // ---- CSR build (once, reused for all 3 layers) ----
    fill_i32<<<(N_NODES + 255) / 256, 256, 0, stream>>>(deg, N_NODES, 1);  // self-loop
    count_deg<<<(N_EDGES + 255) / 256, 256, 0, stream>>>(ei + N_EDGES, deg, N_EDGES);
    scan_deg<<<1, 1024, 0, stream>>>(deg, rowptr, cursor, N_NODES);
    fill_csr<<<(ETOT + 255) / 256, 256, 0, stream>>>(ei, cursor, esrc, N_EDGES, N_NODES);

    // ---- input/weight prep ----
    conv_bf16<<<((N_NODES * F_IN / 4) + 255) / 256, 256, 0, stream>>>(x, xb, N_NODES * F_IN / 4);
    prep_weights<<<(HC * F_IN + 2 * HC * HC + 255) / 256, 256, 0, stream>>>(W1, W2, W3, Wt1, Wt2, Wt3);
    fill_f32<<<2, 256, 0, stream>>>(colstats, 2 * HC, 0.f);

    int agg_blocks = N_NODES / 4;   // exactly 4 waves/block
    dim3 ggrid((N_NODES + 127) / 128, HEADS);

    // ---- layer 1 ----
    {
        gemm_bf16<<<ggrid, 256, 0, stream>>>(xb, Wt1, hfeat, as1, ad1, asb, adb, N_NODES, F_IN);
        gat_aggregate<0><<<agg_blocks, 256, 0, stream>>>(hfeat, asb, adb, rowptr, esrc, b1, gatB);
        bn_stats<<<512, 256, 0, stream>>>(gatB, colsum, colsq, N_NODES);
        bn_finalize<<<1, 256, 0, stream>>>(colsum, colsq, g1, be1, scale, shift, N_NODES);
        bn_apply_elu<<<2048, 256, 0, stream>>>(gatB, scale, shift, xs0, actC, N_NODES);
    }
    // ---- layer 2 ----
    {
        gemm_bf16<<<ggrid, 256, 0, stream>>>(actC, Wt2, hfeat, as2, ad2, asb, adb, N_NODES, HC);
        gat_aggregate<0><<<agg_blocks, 256, 0, stream>>>(hfeat, asb, adb, rowptr, esrc, b2, gatB);
        bn_stats<<<512, 256, 0, stream>>>(gatB, colsum, colsq, N_NODES);
        bn_finalize<<<1, 256, 0, stream>>>(colsum, colsq, g2, be2, scale, shift, N_NODES);
        bn_apply_elu<<<2048, 256, 0, stream>>>(gatB, scale, shift, xs1, actC, N_NODES);
    }
    // ---- layer 3 ----
    {
        gemm_bf16<<<ggrid, 256, 0, stream>>>(actC, Wt3, hfeat, as3, ad3, asb, adb, N_NODES, HC);
        gat_aggregate<1><<<agg_blocks, 256, 0, stream>>>(hfeat, asb, adb, rowptr, esrc, b3, xs2);
    }
    // ---- pool + final linear ----
    pool_final<<<NUM_GRAPHS, 256, 0, stream>>>(xs2, batch, Wlin, blin, pooled_out, out_final);
}